// Round 13
// baseline (317.477 us; speedup 1.0000x reference)
//
#include <hip/hip_runtime.h>
#include <math.h>

#define NN 100000
#define NE 1600000
#define NPB 256                     // nodes per bucket (dst >> 8)
#define NPB_SHIFT 8
#define NB ((NN + NPB - 1) / NPB)   // 391
#define NCHUNK 512                  // binning chunks
#define CH ((NE + NCHUNK - 1) / NCHUNK)  // 3125 edges per chunk
#define NG (NN / 16)                // 6250 MFMA node-groups (exact)
#define LOG2E 1.44269504088896f

typedef __attribute__((ext_vector_type(8))) short short8v;
typedef __attribute__((ext_vector_type(4))) float f32x4;

__device__ __forceinline__ float lrelu(float x) { return fmaxf(x, 0.2f * x); }
__device__ __forceinline__ float elu1(float x) { return x > 0.f ? x : (__expf(x) - 1.f); }
__device__ __forceinline__ float fexp2(float x) {
#if __has_builtin(__builtin_amdgcn_exp2f)
    return __builtin_amdgcn_exp2f(x);
#else
    return exp2f(x);
#endif
}
__device__ __forceinline__ unsigned bf16rne(float f) {
    unsigned u = __float_as_uint(f);
    return (u + 0x7FFFu + ((u >> 16) & 1u)) >> 16;
}
__device__ __forceinline__ float bf16lo(unsigned u) { return __uint_as_float(u << 16); }
__device__ __forceinline__ float bf16hi(unsigned u) {
    return __uint_as_float(u & 0xFFFF0000u);
}
// split x into hi+lo bf16 pair; pack two channels into dwords
__device__ __forceinline__ void split2(float x0, float x1, unsigned& hp, unsigned& lp) {
    unsigned h0 = bf16rne(x0), h1 = bf16rne(x1);
    float r0 = x0 - __uint_as_float(h0 << 16);
    float r1 = x1 - __uint_as_float(h1 << 16);
    hp = h0 | (h1 << 16);
    lp = bf16rne(r0) | (bf16rne(r1) << 16);
}

// ================= binned CSR build =================
// A0: per-chunk histogram -> global (chunk_hist) + arrival-order base within each
// bucket (chunk_base, from the atomicAdd return). binA2 no longer re-histograms.
__global__ void __launch_bounds__(256) k_binA0(const int* __restrict__ dst,
                                               int* __restrict__ bucket_cnt,
                                               int* __restrict__ chunk_hist,
                                               int* __restrict__ chunk_base) {
    __shared__ int hist[NB];
    int t = threadIdx.x;
    for (int b = t; b < NB; b += 256) hist[b] = 0;
    __syncthreads();
    int c0 = blockIdx.x * CH, c1 = min(NE, c0 + CH);
    for (int e = c0 + t; e < c1; e += 256) atomicAdd(&hist[dst[e] >> NPB_SHIFT], 1);
    __syncthreads();
    int gb = blockIdx.x * NB;
    for (int b = t; b < NB; b += 256) {
        int h = hist[b];
        chunk_hist[gb + b] = h;
        chunk_base[gb + b] = h ? atomicAdd(&bucket_cnt[b], h) : 0;
    }
}

__global__ void __launch_bounds__(512) k_bscan(const int* __restrict__ bucket_cnt,
                                               int* __restrict__ bucket_base) {
    __shared__ int s[512];
    int t = threadIdx.x;
    int v = (t < NB) ? bucket_cnt[t] : 0;
    s[t] = v;
    __syncthreads();
    for (int off = 1; off < 512; off <<= 1) {
        int x = (t >= off) ? s[t - off] : 0;
        __syncthreads();
        if (t >= off) s[t] += x;
        __syncthreads();
    }
    if (t < NB) {
        int ex = s[t] - v;
        bucket_base[t] = ex;
        if (t == NB - 1) bucket_base[NB] = s[t];
    }
}

// A2: LDS counting sort of the chunk using the PRECOMPUTED per-chunk histogram
// (no dst re-read, no reservation atomics), then ordered coalesced write-out.
__global__ void __launch_bounds__(256) k_binA2(const int* __restrict__ src,
                                               const int* __restrict__ dst,
                                               const float* __restrict__ ea,
                                               const int* __restrict__ bucket_base,
                                               const int* __restrict__ chunk_hist,
                                               const int* __restrict__ chunk_base,
                                               uint2* __restrict__ binned,
                                               unsigned char* __restrict__ dstb) {
    __shared__ int pre[NB], cursor[NB], base_l[NB];
    __shared__ int psum[256];
    __shared__ uint2 lrec[CH];
    __shared__ int lds_d[CH];
    int t = threadIdx.x;
    int gb = blockIdx.x * NB;
    int c0 = blockIdx.x * CH, c1 = min(NE, c0 + CH);
    int cnt = c1 - c0;
    // local exclusive scan of the precomputed chunk histogram (2 buckets/thread)
    int b0 = t << 1, b1 = b0 + 1;
    int h0 = (b0 < NB) ? chunk_hist[gb + b0] : 0;
    int h1 = (b1 < NB) ? chunk_hist[gb + b1] : 0;
    psum[t] = h0 + h1;
    __syncthreads();
    for (int off = 1; off < 256; off <<= 1) {
        int x = (t >= off) ? psum[t - off] : 0;
        __syncthreads();
        if (t >= off) psum[t] += x;
        __syncthreads();
    }
    int ex = psum[t] - (h0 + h1);
    if (b0 < NB) {
        pre[b0] = ex;
        cursor[b0] = ex;
        base_l[b0] = bucket_base[b0] + chunk_base[gb + b0];
    }
    if (b1 < NB) {
        pre[b1] = ex + h0;
        cursor[b1] = ex + h0;
        base_l[b1] = bucket_base[b1] + chunk_base[gb + b1];
    }
    __syncthreads();
    // pass 2: scatter into LDS at sorted local positions
    for (int i = t; i < cnt; i += 256) {
        int e = c0 + i;
        int d = dst[e];
        int bkt = d >> NPB_SHIFT;
        int lpos = atomicAdd(&cursor[bkt], 1);
        unsigned pk = bf16rne(ea[2 * e]) | (bf16rne(ea[2 * e + 1]) << 16);
        lrec[lpos] = make_uint2((unsigned)src[e], pk);
        lds_d[lpos] = d;
    }
    __syncthreads();
    // pass 3: ordered write-out -> coalesced within bucket segments
    for (int i = t; i < cnt; i += 256) {
        int d = lds_d[i];
        int bkt = d >> NPB_SHIFT;
        int gpos = base_l[bkt] + (i - pre[bkt]);
        binned[gpos] = lrec[i];
        dstb[gpos] = (unsigned char)(d & (NPB - 1));
    }
}

// B: workgroup per bucket -> rowptr + final dst-sorted CSR + fused self-loop la
__global__ void __launch_bounds__(256) k_binB(const int* __restrict__ bucket_base,
                                              const uint2* __restrict__ binned,
                                              const unsigned char* __restrict__ dstb,
                                              int* __restrict__ rowptr,
                                              uint2* __restrict__ edges,
                                              float* __restrict__ la) {
    __shared__ int hist[NPB], pre[NPB], cursor[NPB];
    __shared__ float ea0s[NPB], ea1s[NPB];
    int b = blockIdx.x, t = threadIdx.x;
    int bb = bucket_base[b], be = bucket_base[b + 1];
    int nb0 = b << NPB_SHIFT;
    hist[t] = 0;
    ea0s[t] = 0.f;
    ea1s[t] = 0.f;
    __syncthreads();
    for (int e = bb + t; e < be; e += 256) atomicAdd(&hist[dstb[e]], 1);
    __syncthreads();
    int v = hist[t];
    pre[t] = v;
    __syncthreads();
    for (int off = 1; off < 256; off <<= 1) {
        int x = (t >= off) ? pre[t - off] : 0;
        __syncthreads();
        if (t >= off) pre[t] += x;
        __syncthreads();
    }
    int ex = pre[t] - v;
    if (nb0 + t <= NN) rowptr[nb0 + t] = bb + ex;
    cursor[t] = bb + ex;
    __syncthreads();
    for (int e = bb + t; e < be; e += 256) {
        uint2 rec = binned[e];
        unsigned char d = dstb[e];
        int pos = atomicAdd(&cursor[d], 1);
        edges[pos] = rec;
        atomicAdd(&ea0s[d], bf16lo(rec.y));
        atomicAdd(&ea1s[d], bf16hi(rec.y));
    }
    __syncthreads();
    int n = nb0 + t;
    if (n < NN) {
        float dg = fmaxf((float)v, 1.0f);
        la[2 * n] = ea0s[t] / dg;
        la[2 * n + 1] = ea1s[t] / dg;
    }
}

// ---------- fused constants: me1[8], me2[4], me3[2] (at cbuf+12), vsd[40] (cbuf+16) ----------
__global__ void k_const(const float* __restrict__ We1, const float* __restrict__ aE1,
                        const float* __restrict__ We2, const float* __restrict__ aE2,
                        const float* __restrict__ We3, const float* __restrict__ aE3,
                        const float* __restrict__ W1, const float* __restrict__ aS1,
                        const float* __restrict__ aD1, float* __restrict__ cbuf) {
    int t = threadIdx.x;
    if (t < 8) {
        int d = t >> 2, hd = t & 3;
        float s = 0.f;
        for (int c = 0; c < 32; c++) s += We1[d * 128 + hd * 32 + c] * aE1[hd * 32 + c];
        cbuf[t] = s * LOG2E;
    } else if (t < 12) {
        int idx = t - 8, d = idx >> 1, hd = idx & 1;
        float s = 0.f;
        for (int c = 0; c < 32; c++) s += We2[d * 64 + hd * 32 + c] * aE2[hd * 32 + c];
        cbuf[t] = s * LOG2E;
    } else if (t < 14) {
        cbuf[t] = We3[t - 12] * aE3[0] * LOG2E;
    } else if (t >= 16 && t < 56) {
        int r = (t - 16) % 20, hd = r / 5, i = r % 5;
        const float* a = (t - 16 < 20) ? aS1 : aD1;
        float s = 0.f;
        for (int c = 0; c < 32; c++) s += W1[i * 128 + hd * 32 + c] * a[hd * 32 + c];
        cbuf[t] = s * LOG2E;
    }
}

// ---------- W2 -> transposed hi/lo bf16 split ([col][k], contiguous k for B-frags) ----------
__global__ void k_w2t(const float* __restrict__ W2, unsigned short* __restrict__ W2th,
                      unsigned short* __restrict__ W2tl) {
    int i = blockIdx.x * 256 + threadIdx.x;
    if (i >= 64 * 128) return;
    int c = i >> 7, k = i & 127;
    float v = W2[k * 64 + c];
    unsigned h = bf16rne(v);
    float hf = __uint_as_float(h << 16);
    unsigned lo = bf16rne(v - hf);
    W2th[c * 128 + k] = (unsigned short)h;
    W2tl[c * 128 + k] = (unsigned short)lo;
}

// layer-1 per-node: padded x + logits als1/ald1 (scaled)
__global__ void k_prep1(const float* __restrict__ x, const float* __restrict__ vsd,
                        float4* __restrict__ xp, float4* __restrict__ als1,
                        float4* __restrict__ ald1) {
    int n = blockIdx.x * blockDim.x + threadIdx.x;
    if (n >= NN) return;
    float x0 = x[5 * n], x1 = x[5 * n + 1], x2 = x[5 * n + 2], x3 = x[5 * n + 3],
          x4 = x[5 * n + 4];
    xp[2 * n] = make_float4(x0, x1, x2, x3);
    xp[2 * n + 1] = make_float4(x4, 0.f, 0.f, 0.f);
    float sv[4], dv[4];
#pragma unroll
    for (int hd = 0; hd < 4; hd++) {
        const float* vS = vsd + hd * 5;
        const float* vD = vsd + 20 + hd * 5;
        sv[hd] = x0 * vS[0] + x1 * vS[1] + x2 * vS[2] + x3 * vS[3] + x4 * vS[4];
        dv[hd] = x0 * vD[0] + x1 * vD[1] + x2 * vD[2] + x3 * vD[3] + x4 * vD[4];
    }
    als1[n] = make_float4(sv[0], sv[1], sv[2], sv[3]);
    ald1[n] = make_float4(dv[0], dv[1], dv[2], dv[3]);
}

// ---------- layer 1 agg: thread per (node, head); 4-edge batched ----------
#define AGG1_EDGE(sa, sb, p)                                            \
    a0 += (p) * sa.x; a1 += (p) * sa.y; a2 += (p) * sa.z;               \
    a3 += (p) * sa.w; a4 += (p) * sb;

__global__ void k_agg1(const int* __restrict__ rowptr, const uint2* __restrict__ edges,
                       const float4* __restrict__ xp, const float* __restrict__ als1,
                       const float* __restrict__ ald1, const float* __restrict__ la,
                       const float* __restrict__ me, float* __restrict__ xw) {
    int t = blockIdx.x * blockDim.x + threadIdx.x;
    if (t >= NN * 4) return;
    int n = t >> 2, hd = t & 3;
    float me0 = me[hd], me1 = me[4 + hd];
    float aldn = ald1[t];
    float aself = lrelu(als1[t] + aldn + la[2 * n] * me0 + la[2 * n + 1] * me1);
    int start = rowptr[n], end = rowptr[n + 1];
    float den = 1.f;
    float4 xa = xp[2 * n];
    float xb = xp[2 * n + 1].x;
    float a0 = xa.x, a1 = xa.y, a2 = xa.z, a3 = xa.w, a4 = xb;
    int e = start;
    if ((e & 1) && e < end) {
        uint2 ep = edges[e];
        int s = (int)ep.x;
        float a = lrelu(als1[s * 4 + hd] + aldn + bf16lo(ep.y) * me0 + bf16hi(ep.y) * me1);
        float p = fexp2(a - aself);
        den += p;
        float4 sa = xp[2 * s];
        float sb = xp[2 * s + 1].x;
        AGG1_EDGE(sa, sb, p)
        e++;
    }
    // 4-edge main loop: all loads issued before dependent compute
    for (; e + 3 < end; e += 4) {
        uint4 twoA = *(const uint4*)(edges + e);
        uint4 twoB = *(const uint4*)(edges + e + 2);
        int s0 = (int)twoA.x, s1 = (int)twoA.z;
        int s2 = (int)twoB.x, s3 = (int)twoB.z;
        float l0 = als1[s0 * 4 + hd];
        float l1 = als1[s1 * 4 + hd];
        float l2 = als1[s2 * 4 + hd];
        float l3 = als1[s3 * 4 + hd];
        float4 sa0 = xp[2 * s0]; float sb0 = xp[2 * s0 + 1].x;
        float4 sa1 = xp[2 * s1]; float sb1 = xp[2 * s1 + 1].x;
        float4 sa2 = xp[2 * s2]; float sb2 = xp[2 * s2 + 1].x;
        float4 sa3 = xp[2 * s3]; float sb3 = xp[2 * s3 + 1].x;
        float av0 = lrelu(l0 + aldn + bf16lo(twoA.y) * me0 + bf16hi(twoA.y) * me1);
        float av1 = lrelu(l1 + aldn + bf16lo(twoA.w) * me0 + bf16hi(twoA.w) * me1);
        float av2 = lrelu(l2 + aldn + bf16lo(twoB.y) * me0 + bf16hi(twoB.y) * me1);
        float av3 = lrelu(l3 + aldn + bf16lo(twoB.w) * me0 + bf16hi(twoB.w) * me1);
        float p0 = fexp2(av0 - aself);
        float p1 = fexp2(av1 - aself);
        float p2 = fexp2(av2 - aself);
        float p3 = fexp2(av3 - aself);
        den += (p0 + p1) + (p2 + p3);
        a0 += p0 * sa0.x + p1 * sa1.x + p2 * sa2.x + p3 * sa3.x;
        a1 += p0 * sa0.y + p1 * sa1.y + p2 * sa2.y + p3 * sa3.y;
        a2 += p0 * sa0.z + p1 * sa1.z + p2 * sa2.z + p3 * sa3.z;
        a3 += p0 * sa0.w + p1 * sa1.w + p2 * sa2.w + p3 * sa3.w;
        a4 += p0 * sb0 + p1 * sb1 + p2 * sb2 + p3 * sb3;
    }
    if (e + 1 < end) {
        uint4 two = *(const uint4*)(edges + e);
        int s0 = (int)two.x, s1 = (int)two.z;
        float l0 = als1[s0 * 4 + hd];
        float l1 = als1[s1 * 4 + hd];
        float4 sa0 = xp[2 * s0]; float sb0 = xp[2 * s0 + 1].x;
        float4 sa1 = xp[2 * s1]; float sb1 = xp[2 * s1 + 1].x;
        float av0 = lrelu(l0 + aldn + bf16lo(two.y) * me0 + bf16hi(two.y) * me1);
        float av1 = lrelu(l1 + aldn + bf16lo(two.w) * me0 + bf16hi(two.w) * me1);
        float p0 = fexp2(av0 - aself);
        float p1 = fexp2(av1 - aself);
        den += p0 + p1;
        AGG1_EDGE(sa0, sb0, p0)
        AGG1_EDGE(sa1, sb1, p1)
        e += 2;
    }
    if (e < end) {
        uint2 ep = edges[e];
        int s = (int)ep.x;
        float a = lrelu(als1[s * 4 + hd] + aldn + bf16lo(ep.y) * me0 + bf16hi(ep.y) * me1);
        float p = fexp2(a - aself);
        den += p;
        float4 sa = xp[2 * s];
        float sb = xp[2 * s + 1].x;
        AGG1_EDGE(sa, sb, p)
    }
    float r = 1.f / den;
    float* w = xw + (size_t)n * 20 + hd * 5;
    w[0] = a0 * r;
    w[1] = a1 * r;
    w[2] = a2 * r;
    w[3] = a3 * r;
    w[4] = a4 * r;
}

// ---------- layer 2 transform: PURE MFMA, N-SPLIT (wave = one group x one head) ----
// Wave (m, half) computes output cols [half*32, half*32+32) of group m: the same
// in-register A-fragment build (duplicated across the 2 halves, ~300 VALU) but only
// 24 MFMAs and a clean epilogue split (h2q cols disjoint; als2/ald2 head == half).
// 2x the waves (12.2/SIMD), half the per-wave serial MFMA chain.
__global__ void __launch_bounds__(256) k_l2mfma(
        const float* __restrict__ xw, const float* __restrict__ W1,
        const float* __restrict__ b1,
        const unsigned short* __restrict__ W2th, const unsigned short* __restrict__ W2tl,
        const float* __restrict__ aS2, const float* __restrict__ aD2,
        unsigned short* __restrict__ h2q, float* __restrict__ als2,
        float* __restrict__ ald2) {
    int tl = threadIdx.x;
    int l = tl & 63;
    int wv = blockIdx.x * 4 + (tl >> 6);   // global wave id over NG*2
    int m = wv >> 1, half = wv & 1;
    if (m >= NG) return;
    int g = l >> 4, row16 = l & 15;
    int anode = m * 16 + row16;
    int colA = half * 32 + row16;          // B-row for first tile
    int colB = colA + 16;                  // B-row for second tile
    // 20 xw values of this lane's A-node (5x float4, 80B)
    float w[20];
    {
        const float* wp = xw + (size_t)anode * 20;
#pragma unroll
        for (int i = 0; i < 5; ++i) {
            float4 v = *(const float4*)(wp + i * 4);
            w[i * 4 + 0] = v.x; w[i * 4 + 1] = v.y;
            w[i * 4 + 2] = v.z; w[i * 4 + 3] = v.w;
        }
    }
    f32x4 accA = {0.f, 0.f, 0.f, 0.f}, accB = accA;
#pragma unroll
    for (int kt = 0; kt < 4; ++kt) {
        // ---- build A-fragment: act1 channels ch0..ch0+8 of anode ----
        int ch0 = kt * 32 + g * 8;
        float4 va = *(const float4*)(b1 + ch0);
        float4 vb = *(const float4*)(b1 + ch0 + 4);
#pragma unroll
        for (int i = 0; i < 5; ++i) {
            float wi = w[kt * 5 + i];
            float4 A = *(const float4*)(W1 + i * 128 + ch0);
            float4 B = *(const float4*)(W1 + i * 128 + ch0 + 4);
            va.x += wi * A.x; va.y += wi * A.y; va.z += wi * A.z; va.w += wi * A.w;
            vb.x += wi * B.x; vb.y += wi * B.y; vb.z += wi * B.z; vb.w += wi * B.w;
        }
        unsigned hp0, hp1, hp2, hp3, lp0, lp1, lp2, lp3;
        split2(elu1(va.x), elu1(va.y), hp0, lp0);
        split2(elu1(va.z), elu1(va.w), hp1, lp1);
        split2(elu1(vb.x), elu1(vb.y), hp2, lp2);
        split2(elu1(vb.z), elu1(vb.w), hp3, lp3);
        uint4 uh = make_uint4(hp0, hp1, hp2, hp3);
        uint4 ul = make_uint4(lp0, lp1, lp2, lp3);
        short8v ah = *(short8v*)&uh;
        short8v al = *(short8v*)&ul;
        int kb = kt * 32 + g * 8;
        {
            short8v bh = *(const short8v*)(W2th + colA * 128 + kb);
            short8v bl = *(const short8v*)(W2tl + colA * 128 + kb);
            accA = __builtin_amdgcn_mfma_f32_16x16x32_bf16(ah, bh, accA, 0, 0, 0);
            accA = __builtin_amdgcn_mfma_f32_16x16x32_bf16(al, bh, accA, 0, 0, 0);
            accA = __builtin_amdgcn_mfma_f32_16x16x32_bf16(ah, bl, accA, 0, 0, 0);
        }
        {
            short8v bh = *(const short8v*)(W2th + colB * 128 + kb);
            short8v bl = *(const short8v*)(W2tl + colB * 128 + kb);
            accB = __builtin_amdgcn_mfma_f32_16x16x32_bf16(ah, bh, accB, 0, 0, 0);
            accB = __builtin_amdgcn_mfma_f32_16x16x32_bf16(al, bh, accB, 0, 0, 0);
            accB = __builtin_amdgcn_mfma_f32_16x16x32_bf16(ah, bl, accB, 0, 0, 0);
        }
    }
    // epilogue. D layout: col = l&15 (=ch within tile), row = g*4 + r (=node).
    {
        int nodeb = m * 16 + g * 4;
#pragma unroll
        for (int nt = 0; nt < 2; ++nt) {
            f32x4 A = (nt == 0) ? accA : accB;
#pragma unroll
            for (int r = 0; r < 4; ++r) {
                float v = A[r];
                float u = __shfl_xor(v, 1);
                if (!(l & 1)) {
                    unsigned pk = bf16rne(v) | (bf16rne(u) << 16);
                    int node = nodeb + r;
                    int ch = half * 32 + nt * 16 + row16;   // even
                    *(unsigned*)(h2q + (size_t)node * 64 + ch) = pk;
                }
            }
        }
        float aSvA = aS2[colA], aSvB = aS2[colB];
        float aDvA = aD2[colA], aDvB = aD2[colB];
#pragma unroll
        for (int r = 0; r < 4; ++r) {
            float pS = accA[r] * aSvA + accB[r] * aSvB;
            float pD = accA[r] * aDvA + accB[r] * aDvB;
#pragma unroll
            for (int off = 1; off < 16; off <<= 1) {
                pS += __shfl_xor(pS, off);
                pD += __shfl_xor(pD, off);
            }
            if (row16 == 0) {
                int node = nodeb + r;
                als2[node * 2 + half] = pS * LOG2E;
                ald2[node * 2 + half] = pD * LOG2E;
            }
        }
    }
}

// ---------- layer 2 agg: thread per (node, head-half); 4-edge batched for MLP ----------
#define AGG2_EDGE(u0, u1, p)                                            \
    acc[0] += (p) * bf16lo(u0.x); acc[1] += (p) * bf16hi(u0.x);         \
    acc[2] += (p) * bf16lo(u0.y); acc[3] += (p) * bf16hi(u0.y);         \
    acc[4] += (p) * bf16lo(u0.z); acc[5] += (p) * bf16hi(u0.z);         \
    acc[6] += (p) * bf16lo(u0.w); acc[7] += (p) * bf16hi(u0.w);         \
    acc[8] += (p) * bf16lo(u1.x); acc[9] += (p) * bf16hi(u1.x);         \
    acc[10] += (p) * bf16lo(u1.y); acc[11] += (p) * bf16hi(u1.y);       \
    acc[12] += (p) * bf16lo(u1.z); acc[13] += (p) * bf16hi(u1.z);       \
    acc[14] += (p) * bf16lo(u1.w); acc[15] += (p) * bf16hi(u1.w);

__global__ void k_agg2(const int* __restrict__ rowptr, const uint2* __restrict__ edges,
                       const unsigned short* __restrict__ h2q,
                       const float* __restrict__ als2, const float* __restrict__ ald2,
                       const float* __restrict__ la, const float* __restrict__ me,
                       const float* __restrict__ b2, const float* __restrict__ W3,
                       float* __restrict__ h3) {
    int t = blockIdx.x * blockDim.x + threadIdx.x;
    if (t >= NN * 4) return;
    int n = t >> 2, sub = t & 3, hd = sub >> 1, qh = sub & 1;
    int cbase = hd * 32 + qh * 16;
    float me0 = me[hd], me1 = me[2 + hd];
    float aldn = ald2[n * 2 + hd];
    float aself = lrelu(als2[n * 2 + hd] + aldn + la[2 * n] * me0 + la[2 * n + 1] * me1);
    int start = rowptr[n], end = rowptr[n + 1];
    float den = 1.f;
    float acc[16];
    {
        const uint4* hp = (const uint4*)(h2q + (size_t)n * 64 + cbase);
        uint4 u0 = hp[0], u1 = hp[1];
        acc[0] = bf16lo(u0.x); acc[1] = bf16hi(u0.x);
        acc[2] = bf16lo(u0.y); acc[3] = bf16hi(u0.y);
        acc[4] = bf16lo(u0.z); acc[5] = bf16hi(u0.z);
        acc[6] = bf16lo(u0.w); acc[7] = bf16hi(u0.w);
        acc[8] = bf16lo(u1.x); acc[9] = bf16hi(u1.x);
        acc[10] = bf16lo(u1.y); acc[11] = bf16hi(u1.y);
        acc[12] = bf16lo(u1.z); acc[13] = bf16hi(u1.z);
        acc[14] = bf16lo(u1.w); acc[15] = bf16hi(u1.w);
    }
    int e = start;
    if ((e & 1) && e < end) {
        uint2 ep = edges[e];
        int s = (int)ep.x;
        float a = lrelu(als2[s * 2 + hd] + aldn + bf16lo(ep.y) * me0 + bf16hi(ep.y) * me1);
        float p = fexp2(a - aself);
        den += p;
        const uint4* sp = (const uint4*)(h2q + (size_t)s * 64 + cbase);
        uint4 u0 = sp[0], u1 = sp[1];
        AGG2_EDGE(u0, u1, p)
        e++;
    }
    for (; e + 3 < end; e += 4) {
        uint4 twoA = *(const uint4*)(edges + e);
        uint4 twoB = *(const uint4*)(edges + e + 2);
        int s0 = (int)twoA.x, s1 = (int)twoA.z;
        int s2 = (int)twoB.x, s3 = (int)twoB.z;
        float l0 = als2[s0 * 2 + hd];
        float l1 = als2[s1 * 2 + hd];
        float l2 = als2[s2 * 2 + hd];
        float l3 = als2[s3 * 2 + hd];
        const uint4* sp0 = (const uint4*)(h2q + (size_t)s0 * 64 + cbase);
        const uint4* sp1 = (const uint4*)(h2q + (size_t)s1 * 64 + cbase);
        const uint4* sp2 = (const uint4*)(h2q + (size_t)s2 * 64 + cbase);
        const uint4* sp3 = (const uint4*)(h2q + (size_t)s3 * 64 + cbase);
        uint4 u00 = sp0[0], u01 = sp0[1];
        uint4 u10 = sp1[0], u11 = sp1[1];
        uint4 u20 = sp2[0], u21 = sp2[1];
        uint4 u30 = sp3[0], u31 = sp3[1];
        float av0 = lrelu(l0 + aldn + bf16lo(twoA.y) * me0 + bf16hi(twoA.y) * me1);
        float av1 = lrelu(l1 + aldn + bf16lo(twoA.w) * me0 + bf16hi(twoA.w) * me1);
        float av2 = lrelu(l2 + aldn + bf16lo(twoB.y) * me0 + bf16hi(twoB.y) * me1);
        float av3 = lrelu(l3 + aldn + bf16lo(twoB.w) * me0 + bf16hi(twoB.w) * me1);
        float p0 = fexp2(av0 - aself);
        float p1 = fexp2(av1 - aself);
        float p2 = fexp2(av2 - aself);
        float p3 = fexp2(av3 - aself);
        den += (p0 + p1) + (p2 + p3);
        acc[0] += p0 * bf16lo(u00.x) + p1 * bf16lo(u10.x) + p2 * bf16lo(u20.x) + p3 * bf16lo(u30.x);
        acc[1] += p0 * bf16hi(u00.x) + p1 * bf16hi(u10.x) + p2 * bf16hi(u20.x) + p3 * bf16hi(u30.x);
        acc[2] += p0 * bf16lo(u00.y) + p1 * bf16lo(u10.y) + p2 * bf16lo(u20.y) + p3 * bf16lo(u30.y);
        acc[3] += p0 * bf16hi(u00.y) + p1 * bf16hi(u10.y) + p2 * bf16hi(u20.y) + p3 * bf16hi(u30.y);
        acc[4] += p0 * bf16lo(u00.z) + p1 * bf16lo(u10.z) + p2 * bf16lo(u20.z) + p3 * bf16lo(u30.z);
        acc[5] += p0 * bf16hi(u00.z) + p1 * bf16hi(u10.z) + p2 * bf16hi(u20.z) + p3 * bf16hi(u30.z);
        acc[6] += p0 * bf16lo(u00.w) + p1 * bf16lo(u10.w) + p2 * bf16lo(u20.w) + p3 * bf16lo(u30.w);
        acc[7] += p0 * bf16hi(u00.w) + p1 * bf16hi(u10.w) + p2 * bf16hi(u20.w) + p3 * bf16hi(u30.w);
        acc[8] += p0 * bf16lo(u01.x) + p1 * bf16lo(u11.x) + p2 * bf16lo(u21.x) + p3 * bf16lo(u31.x);
        acc[9] += p0 * bf16hi(u01.x) + p1 * bf16hi(u11.x) + p2 * bf16hi(u21.x) + p3 * bf16hi(u31.x);
        acc[10] += p0 * bf16lo(u01.y) + p1 * bf16lo(u11.y) + p2 * bf16lo(u21.y) + p3 * bf16lo(u31.y);
        acc[11] += p0 * bf16hi(u01.y) + p1 * bf16hi(u11.y) + p2 * bf16hi(u21.y) + p3 * bf16hi(u31.y);
        acc[12] += p0 * bf16lo(u01.z) + p1 * bf16lo(u11.z) + p2 * bf16lo(u21.z) + p3 * bf16lo(u31.z);
        acc[13] += p0 * bf16hi(u01.z) + p1 * bf16hi(u11.z) + p2 * bf16hi(u21.z) + p3 * bf16hi(u31.z);
        acc[14] += p0 * bf16lo(u01.w) + p1 * bf16lo(u11.w) + p2 * bf16lo(u21.w) + p3 * bf16lo(u31.w);
        acc[15] += p0 * bf16hi(u01.w) + p1 * bf16hi(u11.w) + p2 * bf16hi(u21.w) + p3 * bf16hi(u31.w);
    }
    if (e + 1 < end) {
        uint4 two = *(const uint4*)(edges + e);
        int s0 = (int)two.x, s1 = (int)two.z;
        float l0 = als2[s0 * 2 + hd];
        float l1 = als2[s1 * 2 + hd];
        const uint4* sp0 = (const uint4*)(h2q + (size_t)s0 * 64 + cbase);
        const uint4* sp1 = (const uint4*)(h2q + (size_t)s1 * 64 + cbase);
        uint4 u00 = sp0[0], u01 = sp0[1];
        uint4 u10 = sp1[0], u11 = sp1[1];
        float av0 = lrelu(l0 + aldn + bf16lo(two.y) * me0 + bf16hi(two.y) * me1);
        float av1 = lrelu(l1 + aldn + bf16lo(two.w) * me0 + bf16hi(two.w) * me1);
        float p0 = fexp2(av0 - aself);
        float p1 = fexp2(av1 - aself);
        den += p0 + p1;
        AGG2_EDGE(u00, u01, p0)
        AGG2_EDGE(u10, u11, p1)
        e += 2;
    }
    if (e < end) {
        uint2 ep = edges[e];
        int s = (int)ep.x;
        float a = lrelu(als2[s * 2 + hd] + aldn + bf16lo(ep.y) * me0 + bf16hi(ep.y) * me1);
        float p = fexp2(a - aself);
        den += p;
        const uint4* sp = (const uint4*)(h2q + (size_t)s * 64 + cbase);
        uint4 u0 = sp[0], u1 = sp[1];
        AGG2_EDGE(u0, u1, p)
    }
    float r = 1.f / den;
    float part = 0.f;
#pragma unroll
    for (int c = 0; c < 16; c++) {
        float v = elu1(acc[c] * r + b2[cbase + c]);
        part += v * W3[cbase + c];
    }
    part += __shfl_xor(part, 1);
    part += __shfl_xor(part, 2);
    if (sub == 0) h3[n] = part;
}

// ---------- layer 3 agg: 16-lane group per node ----------
__global__ void k_agg3(const int* __restrict__ rowptr, const uint2* __restrict__ edges,
                       const float* __restrict__ h, const float* __restrict__ aS3,
                       const float* __restrict__ aD3, const float* __restrict__ la,
                       const float* __restrict__ me, const float* __restrict__ b,
                       float* __restrict__ out) {
    int tid = blockIdx.x * blockDim.x + threadIdx.x;
    int n = tid >> 4;
    if (n >= NN) return;
    int lane = tid & 15;
    float me0 = me[0], me1 = me[1];
    float aSs = aS3[0] * LOG2E, aDs = aD3[0] * LOG2E;
    float hn = h[n];
    float ald_n = hn * aDs;
    float aself = lrelu(hn * aSs + ald_n + la[2 * n] * me0 + la[2 * n + 1] * me1);
    int start = rowptr[n], end = rowptr[n + 1];
    float den = 0.f, num = 0.f;
    for (int e = start + lane; e < end; e += 16) {
        uint2 ep = edges[e];
        int s = (int)ep.x;
        float hv = h[s];
        float a = lrelu(hv * aSs + ald_n + bf16lo(ep.y) * me0 + bf16hi(ep.y) * me1);
        float p = fexp2(a - aself);
        den += p;
        num += p * hv;
    }
#pragma unroll
    for (int off = 8; off > 0; off >>= 1) {
        den += __shfl_xor(den, off);
        num += __shfl_xor(num, off);
    }
    if (lane == 0) {
        den += 1.f;
        num += hn;
        float v = num / den + b[0];
        out[n] = 1.f / (1.f + __expf(-v));
    }
}

extern "C" void kernel_launch(void* const* d_in, const int* in_sizes, int n_in,
                              void* d_out, int out_size, void* d_ws, size_t ws_size,
                              hipStream_t stream) {
    const float* x   = (const float*)d_in[0];
    const int*   ei  = (const int*)d_in[1];
    const float* ea  = (const float*)d_in[2];
    const float* W1  = (const float*)d_in[3];
    const float* aS1 = (const float*)d_in[4];
    const float* aD1 = (const float*)d_in[5];
    const float* We1 = (const float*)d_in[6];
    const float* aE1 = (const float*)d_in[7];
    const float* b1  = (const float*)d_in[8];
    const float* W2  = (const float*)d_in[9];
    const float* aS2 = (const float*)d_in[10];
    const float* aD2 = (const float*)d_in[11];
    const float* We2 = (const float*)d_in[12];
    const float* aE2 = (const float*)d_in[13];
    const float* b2  = (const float*)d_in[14];
    const float* W3  = (const float*)d_in[15];
    const float* aS3 = (const float*)d_in[16];
    const float* aD3 = (const float*)d_in[17];
    const float* We3 = (const float*)d_in[18];
    const float* aE3 = (const float*)d_in[19];
    const float* b3  = (const float*)d_in[20];

    const int* srcv = ei;
    const int* dstv = ei + NE;

    char* basep = (char*)d_ws;
    size_t off = 0;
    auto alloc = [&](size_t nbytes) -> void* {
        void* p = basep + off;
        off += (nbytes + 255) & ~(size_t)255;
        return p;
    };
    int*    bucket_cnt  = (int*)alloc((size_t)(NB + 1) * 4);
    int*    bucket_base = (int*)alloc((size_t)(NB + 1) * 4);
    int*    chunk_hist  = (int*)alloc((size_t)NCHUNK * NB * 4);   // 800 KB
    int*    chunk_base  = (int*)alloc((size_t)NCHUNK * NB * 4);   // 800 KB
    int*    rowptr      = (int*)alloc((size_t)(NN + 1) * 4);
    uint2*  binned      = (uint2*)alloc((size_t)NE * 8);
    unsigned char* dstb = (unsigned char*)alloc((size_t)NE);
    uint2*  edges       = (uint2*)alloc((size_t)NE * 8);
    float*  la          = (float*)alloc((size_t)NN * 8);
    float*  cbuf        = (float*)alloc(256);   // me1[0..7], me2[8..11], me3[12..13], vsd[16..55]
    float4* xp          = (float4*)alloc((size_t)NN * 32);
    float4* als1        = (float4*)alloc((size_t)NN * 16);
    float4* ald1        = (float4*)alloc((size_t)NN * 16);
    float*  xw          = (float*)alloc((size_t)NN * 80);
    unsigned short* h2q = (unsigned short*)alloc((size_t)NN * 128);
    float*  als2        = (float*)alloc((size_t)NN * 8);
    float*  ald2        = (float*)alloc((size_t)NN * 8);
    float*  h3          = (float*)alloc((size_t)NN * 4);
    unsigned short* W2th = (unsigned short*)alloc(64 * 128 * 2);
    unsigned short* W2tl = (unsigned short*)alloc(64 * 128 * 2);
    (void)ws_size; (void)in_sizes; (void)n_in; (void)out_size;

    float* me1 = cbuf;
    float* me2 = cbuf + 8;
    float* me3 = cbuf + 12;
    float* vsd = cbuf + 16;

    auto cdiv = [](long long a, long long b) { return (int)((a + b - 1) / b); };
    const int BS = 256;

    // ---- binned CSR build (la fused into binB) ----
    hipMemsetAsync(bucket_cnt, 0, (size_t)(NB + 1) * 4, stream);
    k_binA0<<<NCHUNK, 256, 0, stream>>>(dstv, bucket_cnt, chunk_hist, chunk_base);
    k_bscan<<<1, 512, 0, stream>>>(bucket_cnt, bucket_base);
    k_binA2<<<NCHUNK, 256, 0, stream>>>(srcv, dstv, ea, bucket_base, chunk_hist,
                                        chunk_base, binned, dstb);
    k_binB<<<NB, 256, 0, stream>>>(bucket_base, binned, dstb, rowptr, edges, la);

    // ---- all tiny constants + W2 transpose/split ----
    k_const<<<1, 64, 0, stream>>>(We1, aE1, We2, aE2, We3, aE3, W1, aS1, aD1, cbuf);
    k_w2t<<<32, 256, 0, stream>>>(W2, W2th, W2tl);

    // ================= Layer 1: IN=5, H=4, C=32 (ELU) =================
    k_prep1<<<cdiv(NN, BS), BS, 0, stream>>>(x, vsd, xp, als1, ald1);
    k_agg1<<<cdiv((long long)NN * 4, BS), BS, 0, stream>>>(rowptr, edges, xp,
                                                           (const float*)als1,
                                                           (const float*)ald1, la, me1, xw);

    // ================= Layer 2: N-split in-register A-frag MFMA + agg =================
    k_l2mfma<<<cdiv((long long)NG * 2, 4), 256, 0, stream>>>(xw, W1, b1, W2th, W2tl,
                                                             aS2, aD2, h2q, als2, ald2);
    k_agg2<<<cdiv((long long)NN * 4, BS), BS, 0, stream>>>(rowptr, edges, h2q, als2, ald2,
                                                           la, me2, b2, W3, h3);

    // ================= Layer 3: IN=64, H=1, C=1 (sigmoid) =================
    k_agg3<<<cdiv((long long)NN * 16, BS), BS, 0, stream>>>(rowptr, edges, h3, aS3, aD3,
                                                            la, me3, b3, (float*)d_out);
}

// Round 14
// 305.799 us; speedup vs baseline: 1.0382x; 1.0382x over previous
//
#include <hip/hip_runtime.h>
#include <math.h>

#define NN 100000
#define NE 1600000
#define NPB 256                     // nodes per bucket (dst >> 8)
#define NPB_SHIFT 8
#define NB ((NN + NPB - 1) / NPB)   // 391
#define NCHUNK 512                  // binning chunks
#define CH ((NE + NCHUNK - 1) / NCHUNK)  // 3125 edges per chunk
#define NG (NN / 16)                // 6250 MFMA node-groups (exact)
#define LOG2E 1.44269504088896f

typedef __attribute__((ext_vector_type(8))) short short8v;
typedef __attribute__((ext_vector_type(4))) float f32x4;

__device__ __forceinline__ float lrelu(float x) { return fmaxf(x, 0.2f * x); }
__device__ __forceinline__ float elu1(float x) { return x > 0.f ? x : (__expf(x) - 1.f); }
__device__ __forceinline__ float fexp2(float x) {
#if __has_builtin(__builtin_amdgcn_exp2f)
    return __builtin_amdgcn_exp2f(x);
#else
    return exp2f(x);
#endif
}
__device__ __forceinline__ unsigned bf16rne(float f) {
    unsigned u = __float_as_uint(f);
    return (u + 0x7FFFu + ((u >> 16) & 1u)) >> 16;
}
__device__ __forceinline__ float bf16lo(unsigned u) { return __uint_as_float(u << 16); }
__device__ __forceinline__ float bf16hi(unsigned u) {
    return __uint_as_float(u & 0xFFFF0000u);
}
// split x into hi+lo bf16 pair; pack two channels into dwords
__device__ __forceinline__ void split2(float x0, float x1, unsigned& hp, unsigned& lp) {
    unsigned h0 = bf16rne(x0), h1 = bf16rne(x1);
    float r0 = x0 - __uint_as_float(h0 << 16);
    float r1 = x1 - __uint_as_float(h1 << 16);
    hp = h0 | (h1 << 16);
    lp = bf16rne(r0) | (bf16rne(r1) << 16);
}

// ================= binned CSR build =================
// A0: per-chunk histogram -> global (chunk_hist) + arrival-order base within each
// bucket (chunk_base, from the atomicAdd return). binA2 no longer re-histograms.
__global__ void __launch_bounds__(256) k_binA0(const int* __restrict__ dst,
                                               int* __restrict__ bucket_cnt,
                                               int* __restrict__ chunk_hist,
                                               int* __restrict__ chunk_base) {
    __shared__ int hist[NB];
    int t = threadIdx.x;
    for (int b = t; b < NB; b += 256) hist[b] = 0;
    __syncthreads();
    int c0 = blockIdx.x * CH, c1 = min(NE, c0 + CH);
    for (int e = c0 + t; e < c1; e += 256) atomicAdd(&hist[dst[e] >> NPB_SHIFT], 1);
    __syncthreads();
    int gb = blockIdx.x * NB;
    for (int b = t; b < NB; b += 256) {
        int h = hist[b];
        chunk_hist[gb + b] = h;
        chunk_base[gb + b] = h ? atomicAdd(&bucket_cnt[b], h) : 0;
    }
}

__global__ void __launch_bounds__(512) k_bscan(const int* __restrict__ bucket_cnt,
                                               int* __restrict__ bucket_base) {
    __shared__ int s[512];
    int t = threadIdx.x;
    int v = (t < NB) ? bucket_cnt[t] : 0;
    s[t] = v;
    __syncthreads();
    for (int off = 1; off < 512; off <<= 1) {
        int x = (t >= off) ? s[t - off] : 0;
        __syncthreads();
        if (t >= off) s[t] += x;
        __syncthreads();
    }
    if (t < NB) {
        int ex = s[t] - v;
        bucket_base[t] = ex;
        if (t == NB - 1) bucket_base[NB] = s[t];
    }
}

// A2: LDS counting sort of the chunk using the PRECOMPUTED per-chunk histogram
// (no dst re-read, no reservation atomics), then ordered coalesced write-out.
__global__ void __launch_bounds__(256) k_binA2(const int* __restrict__ src,
                                               const int* __restrict__ dst,
                                               const float* __restrict__ ea,
                                               const int* __restrict__ bucket_base,
                                               const int* __restrict__ chunk_hist,
                                               const int* __restrict__ chunk_base,
                                               uint2* __restrict__ binned,
                                               unsigned char* __restrict__ dstb) {
    __shared__ int pre[NB], cursor[NB], base_l[NB];
    __shared__ int psum[256];
    __shared__ uint2 lrec[CH];
    __shared__ int lds_d[CH];
    int t = threadIdx.x;
    int gb = blockIdx.x * NB;
    int c0 = blockIdx.x * CH, c1 = min(NE, c0 + CH);
    int cnt = c1 - c0;
    // local exclusive scan of the precomputed chunk histogram (2 buckets/thread)
    int b0 = t << 1, b1 = b0 + 1;
    int h0 = (b0 < NB) ? chunk_hist[gb + b0] : 0;
    int h1 = (b1 < NB) ? chunk_hist[gb + b1] : 0;
    psum[t] = h0 + h1;
    __syncthreads();
    for (int off = 1; off < 256; off <<= 1) {
        int x = (t >= off) ? psum[t - off] : 0;
        __syncthreads();
        if (t >= off) psum[t] += x;
        __syncthreads();
    }
    int ex = psum[t] - (h0 + h1);
    if (b0 < NB) {
        pre[b0] = ex;
        cursor[b0] = ex;
        base_l[b0] = bucket_base[b0] + chunk_base[gb + b0];
    }
    if (b1 < NB) {
        pre[b1] = ex + h0;
        cursor[b1] = ex + h0;
        base_l[b1] = bucket_base[b1] + chunk_base[gb + b1];
    }
    __syncthreads();
    // pass 2: scatter into LDS at sorted local positions
    for (int i = t; i < cnt; i += 256) {
        int e = c0 + i;
        int d = dst[e];
        int bkt = d >> NPB_SHIFT;
        int lpos = atomicAdd(&cursor[bkt], 1);
        unsigned pk = bf16rne(ea[2 * e]) | (bf16rne(ea[2 * e + 1]) << 16);
        lrec[lpos] = make_uint2((unsigned)src[e], pk);
        lds_d[lpos] = d;
    }
    __syncthreads();
    // pass 3: ordered write-out -> coalesced within bucket segments
    for (int i = t; i < cnt; i += 256) {
        int d = lds_d[i];
        int bkt = d >> NPB_SHIFT;
        int gpos = base_l[bkt] + (i - pre[bkt]);
        binned[gpos] = lrec[i];
        dstb[gpos] = (unsigned char)(d & (NPB - 1));
    }
}

// B: workgroup per bucket -> rowptr + final dst-sorted CSR + fused self-loop la
__global__ void __launch_bounds__(256) k_binB(const int* __restrict__ bucket_base,
                                              const uint2* __restrict__ binned,
                                              const unsigned char* __restrict__ dstb,
                                              int* __restrict__ rowptr,
                                              uint2* __restrict__ edges,
                                              float* __restrict__ la) {
    __shared__ int hist[NPB], pre[NPB], cursor[NPB];
    __shared__ float ea0s[NPB], ea1s[NPB];
    int b = blockIdx.x, t = threadIdx.x;
    int bb = bucket_base[b], be = bucket_base[b + 1];
    int nb0 = b << NPB_SHIFT;
    hist[t] = 0;
    ea0s[t] = 0.f;
    ea1s[t] = 0.f;
    __syncthreads();
    for (int e = bb + t; e < be; e += 256) atomicAdd(&hist[dstb[e]], 1);
    __syncthreads();
    int v = hist[t];
    pre[t] = v;
    __syncthreads();
    for (int off = 1; off < 256; off <<= 1) {
        int x = (t >= off) ? pre[t - off] : 0;
        __syncthreads();
        if (t >= off) pre[t] += x;
        __syncthreads();
    }
    int ex = pre[t] - v;
    if (nb0 + t <= NN) rowptr[nb0 + t] = bb + ex;
    cursor[t] = bb + ex;
    __syncthreads();
    for (int e = bb + t; e < be; e += 256) {
        uint2 rec = binned[e];
        unsigned char d = dstb[e];
        int pos = atomicAdd(&cursor[d], 1);
        edges[pos] = rec;
        atomicAdd(&ea0s[d], bf16lo(rec.y));
        atomicAdd(&ea1s[d], bf16hi(rec.y));
    }
    __syncthreads();
    int n = nb0 + t;
    if (n < NN) {
        float dg = fmaxf((float)v, 1.0f);
        la[2 * n] = ea0s[t] / dg;
        la[2 * n + 1] = ea1s[t] / dg;
    }
}

// ---------- fused constants + W2 transpose/split (one launch, 33 blocks) ----------
// block 0: me1[8], me2[4], me3[2] (cbuf+12), vsd[40] (cbuf+16)
// blocks 1..32: W2 -> transposed hi/lo bf16 split ([col][k])
__global__ void __launch_bounds__(256) k_constw(
        const float* __restrict__ We1, const float* __restrict__ aE1,
        const float* __restrict__ We2, const float* __restrict__ aE2,
        const float* __restrict__ We3, const float* __restrict__ aE3,
        const float* __restrict__ W1, const float* __restrict__ aS1,
        const float* __restrict__ aD1, float* __restrict__ cbuf,
        const float* __restrict__ W2, unsigned short* __restrict__ W2th,
        unsigned short* __restrict__ W2tl) {
    if (blockIdx.x == 0) {
        int t = threadIdx.x;
        if (t < 8) {
            int d = t >> 2, hd = t & 3;
            float s = 0.f;
            for (int c = 0; c < 32; c++) s += We1[d * 128 + hd * 32 + c] * aE1[hd * 32 + c];
            cbuf[t] = s * LOG2E;
        } else if (t < 12) {
            int idx = t - 8, d = idx >> 1, hd = idx & 1;
            float s = 0.f;
            for (int c = 0; c < 32; c++) s += We2[d * 64 + hd * 32 + c] * aE2[hd * 32 + c];
            cbuf[t] = s * LOG2E;
        } else if (t < 14) {
            cbuf[t] = We3[t - 12] * aE3[0] * LOG2E;
        } else if (t >= 16 && t < 56) {
            int r = (t - 16) % 20, hd = r / 5, i = r % 5;
            const float* a = (t - 16 < 20) ? aS1 : aD1;
            float s = 0.f;
            for (int c = 0; c < 32; c++) s += W1[i * 128 + hd * 32 + c] * a[hd * 32 + c];
            cbuf[t] = s * LOG2E;
        }
    } else {
        int i = (blockIdx.x - 1) * 256 + threadIdx.x;
        if (i >= 64 * 128) return;
        int c = i >> 7, k = i & 127;
        float v = W2[k * 64 + c];
        unsigned h = bf16rne(v);
        float hf = __uint_as_float(h << 16);
        unsigned lo = bf16rne(v - hf);
        W2th[c * 128 + k] = (unsigned short)h;
        W2tl[c * 128 + k] = (unsigned short)lo;
    }
}

// layer-1 per-node: padded x + logits als1/ald1 (scaled)
__global__ void k_prep1(const float* __restrict__ x, const float* __restrict__ vsd,
                        float4* __restrict__ xp, float4* __restrict__ als1,
                        float4* __restrict__ ald1) {
    int n = blockIdx.x * blockDim.x + threadIdx.x;
    if (n >= NN) return;
    float x0 = x[5 * n], x1 = x[5 * n + 1], x2 = x[5 * n + 2], x3 = x[5 * n + 3],
          x4 = x[5 * n + 4];
    xp[2 * n] = make_float4(x0, x1, x2, x3);
    xp[2 * n + 1] = make_float4(x4, 0.f, 0.f, 0.f);
    float sv[4], dv[4];
#pragma unroll
    for (int hd = 0; hd < 4; hd++) {
        const float* vS = vsd + hd * 5;
        const float* vD = vsd + 20 + hd * 5;
        sv[hd] = x0 * vS[0] + x1 * vS[1] + x2 * vS[2] + x3 * vS[3] + x4 * vS[4];
        dv[hd] = x0 * vD[0] + x1 * vD[1] + x2 * vD[2] + x3 * vD[3] + x4 * vD[4];
    }
    als1[n] = make_float4(sv[0], sv[1], sv[2], sv[3]);
    ald1[n] = make_float4(dv[0], dv[1], dv[2], dv[3]);
}

// ---------- layer 1 agg: thread per (node, head); 4-edge batched ----------
#define AGG1_EDGE(sa, sb, p)                                            \
    a0 += (p) * sa.x; a1 += (p) * sa.y; a2 += (p) * sa.z;               \
    a3 += (p) * sa.w; a4 += (p) * sb;

__global__ void k_agg1(const int* __restrict__ rowptr, const uint2* __restrict__ edges,
                       const float4* __restrict__ xp, const float* __restrict__ als1,
                       const float* __restrict__ ald1, const float* __restrict__ la,
                       const float* __restrict__ me, float* __restrict__ xw) {
    int t = blockIdx.x * blockDim.x + threadIdx.x;
    if (t >= NN * 4) return;
    int n = t >> 2, hd = t & 3;
    float me0 = me[hd], me1 = me[4 + hd];
    float aldn = ald1[t];
    float aself = lrelu(als1[t] + aldn + la[2 * n] * me0 + la[2 * n + 1] * me1);
    int start = rowptr[n], end = rowptr[n + 1];
    float den = 1.f;
    float4 xa = xp[2 * n];
    float xb = xp[2 * n + 1].x;
    float a0 = xa.x, a1 = xa.y, a2 = xa.z, a3 = xa.w, a4 = xb;
    int e = start;
    if ((e & 1) && e < end) {
        uint2 ep = edges[e];
        int s = (int)ep.x;
        float a = lrelu(als1[s * 4 + hd] + aldn + bf16lo(ep.y) * me0 + bf16hi(ep.y) * me1);
        float p = fexp2(a - aself);
        den += p;
        float4 sa = xp[2 * s];
        float sb = xp[2 * s + 1].x;
        AGG1_EDGE(sa, sb, p)
        e++;
    }
    // 4-edge main loop: all loads issued before dependent compute
    for (; e + 3 < end; e += 4) {
        uint4 twoA = *(const uint4*)(edges + e);
        uint4 twoB = *(const uint4*)(edges + e + 2);
        int s0 = (int)twoA.x, s1 = (int)twoA.z;
        int s2 = (int)twoB.x, s3 = (int)twoB.z;
        float l0 = als1[s0 * 4 + hd];
        float l1 = als1[s1 * 4 + hd];
        float l2 = als1[s2 * 4 + hd];
        float l3 = als1[s3 * 4 + hd];
        float4 sa0 = xp[2 * s0]; float sb0 = xp[2 * s0 + 1].x;
        float4 sa1 = xp[2 * s1]; float sb1 = xp[2 * s1 + 1].x;
        float4 sa2 = xp[2 * s2]; float sb2 = xp[2 * s2 + 1].x;
        float4 sa3 = xp[2 * s3]; float sb3 = xp[2 * s3 + 1].x;
        float av0 = lrelu(l0 + aldn + bf16lo(twoA.y) * me0 + bf16hi(twoA.y) * me1);
        float av1 = lrelu(l1 + aldn + bf16lo(twoA.w) * me0 + bf16hi(twoA.w) * me1);
        float av2 = lrelu(l2 + aldn + bf16lo(twoB.y) * me0 + bf16hi(twoB.y) * me1);
        float av3 = lrelu(l3 + aldn + bf16lo(twoB.w) * me0 + bf16hi(twoB.w) * me1);
        float p0 = fexp2(av0 - aself);
        float p1 = fexp2(av1 - aself);
        float p2 = fexp2(av2 - aself);
        float p3 = fexp2(av3 - aself);
        den += (p0 + p1) + (p2 + p3);
        a0 += p0 * sa0.x + p1 * sa1.x + p2 * sa2.x + p3 * sa3.x;
        a1 += p0 * sa0.y + p1 * sa1.y + p2 * sa2.y + p3 * sa3.y;
        a2 += p0 * sa0.z + p1 * sa1.z + p2 * sa2.z + p3 * sa3.z;
        a3 += p0 * sa0.w + p1 * sa1.w + p2 * sa2.w + p3 * sa3.w;
        a4 += p0 * sb0 + p1 * sb1 + p2 * sb2 + p3 * sb3;
    }
    if (e + 1 < end) {
        uint4 two = *(const uint4*)(edges + e);
        int s0 = (int)two.x, s1 = (int)two.z;
        float l0 = als1[s0 * 4 + hd];
        float l1 = als1[s1 * 4 + hd];
        float4 sa0 = xp[2 * s0]; float sb0 = xp[2 * s0 + 1].x;
        float4 sa1 = xp[2 * s1]; float sb1 = xp[2 * s1 + 1].x;
        float av0 = lrelu(l0 + aldn + bf16lo(two.y) * me0 + bf16hi(two.y) * me1);
        float av1 = lrelu(l1 + aldn + bf16lo(two.w) * me0 + bf16hi(two.w) * me1);
        float p0 = fexp2(av0 - aself);
        float p1 = fexp2(av1 - aself);
        den += p0 + p1;
        AGG1_EDGE(sa0, sb0, p0)
        AGG1_EDGE(sa1, sb1, p1)
        e += 2;
    }
    if (e < end) {
        uint2 ep = edges[e];
        int s = (int)ep.x;
        float a = lrelu(als1[s * 4 + hd] + aldn + bf16lo(ep.y) * me0 + bf16hi(ep.y) * me1);
        float p = fexp2(a - aself);
        den += p;
        float4 sa = xp[2 * s];
        float sb = xp[2 * s + 1].x;
        AGG1_EDGE(sa, sb, p)
    }
    float r = 1.f / den;
    float* w = xw + (size_t)n * 20 + hd * 5;
    w[0] = a0 * r;
    w[1] = a1 * r;
    w[2] = a2 * r;
    w[3] = a3 * r;
    w[4] = a4 * r;
}

// ---------- layer 2 transform: PURE MFMA, A-fragments IN-REGISTER (R12 form) ----------
// 1 wave per block (grid = NG): free wave placement across SIMDs, zero LDS.
__global__ void __launch_bounds__(64) k_l2mfma(
        const float* __restrict__ xw, const float* __restrict__ W1,
        const float* __restrict__ b1,
        const unsigned short* __restrict__ W2th, const unsigned short* __restrict__ W2tl,
        const float* __restrict__ aS2, const float* __restrict__ aD2,
        unsigned short* __restrict__ h2q, float* __restrict__ als2,
        float* __restrict__ ald2) {
    int l = threadIdx.x;
    int m = blockIdx.x;
    if (m >= NG) return;
    int g = l >> 4, row16 = l & 15;
    int anode = m * 16 + row16;
    // 20 xw values of this lane's A-node (5x float4, 80B)
    float w[20];
    {
        const float* wp = xw + (size_t)anode * 20;
#pragma unroll
        for (int i = 0; i < 5; ++i) {
            float4 v = *(const float4*)(wp + i * 4);
            w[i * 4 + 0] = v.x; w[i * 4 + 1] = v.y;
            w[i * 4 + 2] = v.z; w[i * 4 + 3] = v.w;
        }
    }
    f32x4 acc0 = {0.f, 0.f, 0.f, 0.f}, acc1 = acc0, acc2 = acc0, acc3 = acc0;
#pragma unroll
    for (int kt = 0; kt < 4; ++kt) {
        // ---- build A-fragment: act1 channels ch0..ch0+8 of anode ----
        int ch0 = kt * 32 + g * 8;
        float4 va = *(const float4*)(b1 + ch0);
        float4 vb = *(const float4*)(b1 + ch0 + 4);
#pragma unroll
        for (int i = 0; i < 5; ++i) {
            float wi = w[kt * 5 + i];
            float4 A = *(const float4*)(W1 + i * 128 + ch0);
            float4 B = *(const float4*)(W1 + i * 128 + ch0 + 4);
            va.x += wi * A.x; va.y += wi * A.y; va.z += wi * A.z; va.w += wi * A.w;
            vb.x += wi * B.x; vb.y += wi * B.y; vb.z += wi * B.z; vb.w += wi * B.w;
        }
        unsigned hp0, hp1, hp2, hp3, lp0, lp1, lp2, lp3;
        split2(elu1(va.x), elu1(va.y), hp0, lp0);
        split2(elu1(va.z), elu1(va.w), hp1, lp1);
        split2(elu1(vb.x), elu1(vb.y), hp2, lp2);
        split2(elu1(vb.z), elu1(vb.w), hp3, lp3);
        uint4 uh = make_uint4(hp0, hp1, hp2, hp3);
        uint4 ul = make_uint4(lp0, lp1, lp2, lp3);
        short8v ah = *(short8v*)&uh;
        short8v al = *(short8v*)&ul;
        int kb = kt * 32 + g * 8;
        {
            short8v bh = *(const short8v*)(W2th + row16 * 128 + kb);
            short8v bl = *(const short8v*)(W2tl + row16 * 128 + kb);
            acc0 = __builtin_amdgcn_mfma_f32_16x16x32_bf16(ah, bh, acc0, 0, 0, 0);
            acc0 = __builtin_amdgcn_mfma_f32_16x16x32_bf16(al, bh, acc0, 0, 0, 0);
            acc0 = __builtin_amdgcn_mfma_f32_16x16x32_bf16(ah, bl, acc0, 0, 0, 0);
        }
        {
            short8v bh = *(const short8v*)(W2th + (16 + row16) * 128 + kb);
            short8v bl = *(const short8v*)(W2tl + (16 + row16) * 128 + kb);
            acc1 = __builtin_amdgcn_mfma_f32_16x16x32_bf16(ah, bh, acc1, 0, 0, 0);
            acc1 = __builtin_amdgcn_mfma_f32_16x16x32_bf16(al, bh, acc1, 0, 0, 0);
            acc1 = __builtin_amdgcn_mfma_f32_16x16x32_bf16(ah, bl, acc1, 0, 0, 0);
        }
        {
            short8v bh = *(const short8v*)(W2th + (32 + row16) * 128 + kb);
            short8v bl = *(const short8v*)(W2tl + (32 + row16) * 128 + kb);
            acc2 = __builtin_amdgcn_mfma_f32_16x16x32_bf16(ah, bh, acc2, 0, 0, 0);
            acc2 = __builtin_amdgcn_mfma_f32_16x16x32_bf16(al, bh, acc2, 0, 0, 0);
            acc2 = __builtin_amdgcn_mfma_f32_16x16x32_bf16(ah, bl, acc2, 0, 0, 0);
        }
        {
            short8v bh = *(const short8v*)(W2th + (48 + row16) * 128 + kb);
            short8v bl = *(const short8v*)(W2tl + (48 + row16) * 128 + kb);
            acc3 = __builtin_amdgcn_mfma_f32_16x16x32_bf16(ah, bh, acc3, 0, 0, 0);
            acc3 = __builtin_amdgcn_mfma_f32_16x16x32_bf16(al, bh, acc3, 0, 0, 0);
            acc3 = __builtin_amdgcn_mfma_f32_16x16x32_bf16(ah, bl, acc3, 0, 0, 0);
        }
    }
    // epilogue (R6-verified). D layout: col = l&15 (=ch), row = g*4 + r (=node).
    {
        int nodeb = m * 16 + g * 4;
#pragma unroll
        for (int nt = 0; nt < 4; ++nt) {
            f32x4 A = (nt == 0) ? acc0 : (nt == 1) ? acc1 : (nt == 2) ? acc2 : acc3;
#pragma unroll
            for (int r = 0; r < 4; ++r) {
                float v = A[r];
                float u = __shfl_xor(v, 1);
                if (!(l & 1)) {
                    unsigned pk = bf16rne(v) | (bf16rne(u) << 16);
                    int node = nodeb + r;
                    int ch = nt * 16 + row16;   // even
                    *(unsigned*)(h2q + (size_t)node * 64 + ch) = pk;
                }
            }
        }
        float aSv0 = aS2[row16], aSv1 = aS2[16 + row16];
        float aSv2 = aS2[32 + row16], aSv3 = aS2[48 + row16];
        float aDv0 = aD2[row16], aDv1 = aD2[16 + row16];
        float aDv2 = aD2[32 + row16], aDv3 = aD2[48 + row16];
#pragma unroll
        for (int r = 0; r < 4; ++r) {
            float pS0 = acc0[r] * aSv0 + acc1[r] * aSv1;
            float pS1 = acc2[r] * aSv2 + acc3[r] * aSv3;
            float pD0 = acc0[r] * aDv0 + acc1[r] * aDv1;
            float pD1 = acc2[r] * aDv2 + acc3[r] * aDv3;
#pragma unroll
            for (int off = 1; off < 16; off <<= 1) {
                pS0 += __shfl_xor(pS0, off);
                pS1 += __shfl_xor(pS1, off);
                pD0 += __shfl_xor(pD0, off);
                pD1 += __shfl_xor(pD1, off);
            }
            if (row16 == 0) {
                int node = nodeb + r;
                als2[node * 2 + 0] = pS0 * LOG2E;
                als2[node * 2 + 1] = pS1 * LOG2E;
                ald2[node * 2 + 0] = pD0 * LOG2E;
                ald2[node * 2 + 1] = pD1 * LOG2E;
            }
        }
    }
}

// ---------- layer 2 agg: thread per (node, head-half); 4-edge batched for MLP ----------
#define AGG2_EDGE(u0, u1, p)                                            \
    acc[0] += (p) * bf16lo(u0.x); acc[1] += (p) * bf16hi(u0.x);         \
    acc[2] += (p) * bf16lo(u0.y); acc[3] += (p) * bf16hi(u0.y);         \
    acc[4] += (p) * bf16lo(u0.z); acc[5] += (p) * bf16hi(u0.z);         \
    acc[6] += (p) * bf16lo(u0.w); acc[7] += (p) * bf16hi(u0.w);         \
    acc[8] += (p) * bf16lo(u1.x); acc[9] += (p) * bf16hi(u1.x);         \
    acc[10] += (p) * bf16lo(u1.y); acc[11] += (p) * bf16hi(u1.y);       \
    acc[12] += (p) * bf16lo(u1.z); acc[13] += (p) * bf16hi(u1.z);       \
    acc[14] += (p) * bf16lo(u1.w); acc[15] += (p) * bf16hi(u1.w);

__global__ void k_agg2(const int* __restrict__ rowptr, const uint2* __restrict__ edges,
                       const unsigned short* __restrict__ h2q,
                       const float* __restrict__ als2, const float* __restrict__ ald2,
                       const float* __restrict__ la, const float* __restrict__ me,
                       const float* __restrict__ b2, const float* __restrict__ W3,
                       float* __restrict__ h3) {
    int t = blockIdx.x * blockDim.x + threadIdx.x;
    if (t >= NN * 4) return;
    int n = t >> 2, sub = t & 3, hd = sub >> 1, qh = sub & 1;
    int cbase = hd * 32 + qh * 16;
    float me0 = me[hd], me1 = me[2 + hd];
    float aldn = ald2[n * 2 + hd];
    float aself = lrelu(als2[n * 2 + hd] + aldn + la[2 * n] * me0 + la[2 * n + 1] * me1);
    int start = rowptr[n], end = rowptr[n + 1];
    float den = 1.f;
    float acc[16];
    {
        const uint4* hp = (const uint4*)(h2q + (size_t)n * 64 + cbase);
        uint4 u0 = hp[0], u1 = hp[1];
        acc[0] = bf16lo(u0.x); acc[1] = bf16hi(u0.x);
        acc[2] = bf16lo(u0.y); acc[3] = bf16hi(u0.y);
        acc[4] = bf16lo(u0.z); acc[5] = bf16hi(u0.z);
        acc[6] = bf16lo(u0.w); acc[7] = bf16hi(u0.w);
        acc[8] = bf16lo(u1.x); acc[9] = bf16hi(u1.x);
        acc[10] = bf16lo(u1.y); acc[11] = bf16hi(u1.y);
        acc[12] = bf16lo(u1.z); acc[13] = bf16hi(u1.z);
        acc[14] = bf16lo(u1.w); acc[15] = bf16hi(u1.w);
    }
    int e = start;
    if ((e & 1) && e < end) {
        uint2 ep = edges[e];
        int s = (int)ep.x;
        float a = lrelu(als2[s * 2 + hd] + aldn + bf16lo(ep.y) * me0 + bf16hi(ep.y) * me1);
        float p = fexp2(a - aself);
        den += p;
        const uint4* sp = (const uint4*)(h2q + (size_t)s * 64 + cbase);
        uint4 u0 = sp[0], u1 = sp[1];
        AGG2_EDGE(u0, u1, p)
        e++;
    }
    for (; e + 3 < end; e += 4) {
        uint4 twoA = *(const uint4*)(edges + e);
        uint4 twoB = *(const uint4*)(edges + e + 2);
        int s0 = (int)twoA.x, s1 = (int)twoA.z;
        int s2 = (int)twoB.x, s3 = (int)twoB.z;
        float l0 = als2[s0 * 2 + hd];
        float l1 = als2[s1 * 2 + hd];
        float l2 = als2[s2 * 2 + hd];
        float l3 = als2[s3 * 2 + hd];
        const uint4* sp0 = (const uint4*)(h2q + (size_t)s0 * 64 + cbase);
        const uint4* sp1 = (const uint4*)(h2q + (size_t)s1 * 64 + cbase);
        const uint4* sp2 = (const uint4*)(h2q + (size_t)s2 * 64 + cbase);
        const uint4* sp3 = (const uint4*)(h2q + (size_t)s3 * 64 + cbase);
        uint4 u00 = sp0[0], u01 = sp0[1];
        uint4 u10 = sp1[0], u11 = sp1[1];
        uint4 u20 = sp2[0], u21 = sp2[1];
        uint4 u30 = sp3[0], u31 = sp3[1];
        float av0 = lrelu(l0 + aldn + bf16lo(twoA.y) * me0 + bf16hi(twoA.y) * me1);
        float av1 = lrelu(l1 + aldn + bf16lo(twoA.w) * me0 + bf16hi(twoA.w) * me1);
        float av2 = lrelu(l2 + aldn + bf16lo(twoB.y) * me0 + bf16hi(twoB.y) * me1);
        float av3 = lrelu(l3 + aldn + bf16lo(twoB.w) * me0 + bf16hi(twoB.w) * me1);
        float p0 = fexp2(av0 - aself);
        float p1 = fexp2(av1 - aself);
        float p2 = fexp2(av2 - aself);
        float p3 = fexp2(av3 - aself);
        den += (p0 + p1) + (p2 + p3);
        acc[0] += p0 * bf16lo(u00.x) + p1 * bf16lo(u10.x) + p2 * bf16lo(u20.x) + p3 * bf16lo(u30.x);
        acc[1] += p0 * bf16hi(u00.x) + p1 * bf16hi(u10.x) + p2 * bf16hi(u20.x) + p3 * bf16hi(u30.x);
        acc[2] += p0 * bf16lo(u00.y) + p1 * bf16lo(u10.y) + p2 * bf16lo(u20.y) + p3 * bf16lo(u30.y);
        acc[3] += p0 * bf16hi(u00.y) + p1 * bf16hi(u10.y) + p2 * bf16hi(u20.y) + p3 * bf16hi(u30.y);
        acc[4] += p0 * bf16lo(u00.z) + p1 * bf16lo(u10.z) + p2 * bf16lo(u20.z) + p3 * bf16lo(u30.z);
        acc[5] += p0 * bf16hi(u00.z) + p1 * bf16hi(u10.z) + p2 * bf16hi(u20.z) + p3 * bf16hi(u30.z);
        acc[6] += p0 * bf16lo(u00.w) + p1 * bf16lo(u10.w) + p2 * bf16lo(u20.w) + p3 * bf16lo(u30.w);
        acc[7] += p0 * bf16hi(u00.w) + p1 * bf16hi(u10.w) + p2 * bf16hi(u20.w) + p3 * bf16hi(u30.w);
        acc[8] += p0 * bf16lo(u01.x) + p1 * bf16lo(u11.x) + p2 * bf16lo(u21.x) + p3 * bf16lo(u31.x);
        acc[9] += p0 * bf16hi(u01.x) + p1 * bf16hi(u11.x) + p2 * bf16hi(u21.x) + p3 * bf16hi(u31.x);
        acc[10] += p0 * bf16lo(u01.y) + p1 * bf16lo(u11.y) + p2 * bf16lo(u21.y) + p3 * bf16lo(u31.y);
        acc[11] += p0 * bf16hi(u01.y) + p1 * bf16hi(u11.y) + p2 * bf16hi(u21.y) + p3 * bf16hi(u31.y);
        acc[12] += p0 * bf16lo(u01.z) + p1 * bf16lo(u11.z) + p2 * bf16lo(u21.z) + p3 * bf16lo(u31.z);
        acc[13] += p0 * bf16hi(u01.z) + p1 * bf16hi(u11.z) + p2 * bf16hi(u21.z) + p3 * bf16hi(u31.z);
        acc[14] += p0 * bf16lo(u01.w) + p1 * bf16lo(u11.w) + p2 * bf16lo(u21.w) + p3 * bf16lo(u31.w);
        acc[15] += p0 * bf16hi(u01.w) + p1 * bf16hi(u11.w) + p2 * bf16hi(u21.w) + p3 * bf16hi(u31.w);
    }
    if (e + 1 < end) {
        uint4 two = *(const uint4*)(edges + e);
        int s0 = (int)two.x, s1 = (int)two.z;
        float l0 = als2[s0 * 2 + hd];
        float l1 = als2[s1 * 2 + hd];
        const uint4* sp0 = (const uint4*)(h2q + (size_t)s0 * 64 + cbase);
        const uint4* sp1 = (const uint4*)(h2q + (size_t)s1 * 64 + cbase);
        uint4 u00 = sp0[0], u01 = sp0[1];
        uint4 u10 = sp1[0], u11 = sp1[1];
        float av0 = lrelu(l0 + aldn + bf16lo(two.y) * me0 + bf16hi(two.y) * me1);
        float av1 = lrelu(l1 + aldn + bf16lo(two.w) * me0 + bf16hi(two.w) * me1);
        float p0 = fexp2(av0 - aself);
        float p1 = fexp2(av1 - aself);
        den += p0 + p1;
        AGG2_EDGE(u00, u01, p0)
        AGG2_EDGE(u10, u11, p1)
        e += 2;
    }
    if (e < end) {
        uint2 ep = edges[e];
        int s = (int)ep.x;
        float a = lrelu(als2[s * 2 + hd] + aldn + bf16lo(ep.y) * me0 + bf16hi(ep.y) * me1);
        float p = fexp2(a - aself);
        den += p;
        const uint4* sp = (const uint4*)(h2q + (size_t)s * 64 + cbase);
        uint4 u0 = sp[0], u1 = sp[1];
        AGG2_EDGE(u0, u1, p)
    }
    float r = 1.f / den;
    float part = 0.f;
#pragma unroll
    for (int c = 0; c < 16; c++) {
        float v = elu1(acc[c] * r + b2[cbase + c]);
        part += v * W3[cbase + c];
    }
    part += __shfl_xor(part, 1);
    part += __shfl_xor(part, 2);
    if (sub == 0) h3[n] = part;
}

// ---------- layer 3 agg: 16-lane group per node ----------
__global__ void k_agg3(const int* __restrict__ rowptr, const uint2* __restrict__ edges,
                       const float* __restrict__ h, const float* __restrict__ aS3,
                       const float* __restrict__ aD3, const float* __restrict__ la,
                       const float* __restrict__ me, const float* __restrict__ b,
                       float* __restrict__ out) {
    int tid = blockIdx.x * blockDim.x + threadIdx.x;
    int n = tid >> 4;
    if (n >= NN) return;
    int lane = tid & 15;
    float me0 = me[0], me1 = me[1];
    float aSs = aS3[0] * LOG2E, aDs = aD3[0] * LOG2E;
    float hn = h[n];
    float ald_n = hn * aDs;
    float aself = lrelu(hn * aSs + ald_n + la[2 * n] * me0 + la[2 * n + 1] * me1);
    int start = rowptr[n], end = rowptr[n + 1];
    float den = 0.f, num = 0.f;
    for (int e = start + lane; e < end; e += 16) {
        uint2 ep = edges[e];
        int s = (int)ep.x;
        float hv = h[s];
        float a = lrelu(hv * aSs + ald_n + bf16lo(ep.y) * me0 + bf16hi(ep.y) * me1);
        float p = fexp2(a - aself);
        den += p;
        num += p * hv;
    }
#pragma unroll
    for (int off = 8; off > 0; off >>= 1) {
        den += __shfl_xor(den, off);
        num += __shfl_xor(num, off);
    }
    if (lane == 0) {
        den += 1.f;
        num += hn;
        float v = num / den + b[0];
        out[n] = 1.f / (1.f + __expf(-v));
    }
}

extern "C" void kernel_launch(void* const* d_in, const int* in_sizes, int n_in,
                              void* d_out, int out_size, void* d_ws, size_t ws_size,
                              hipStream_t stream) {
    const float* x   = (const float*)d_in[0];
    const int*   ei  = (const int*)d_in[1];
    const float* ea  = (const float*)d_in[2];
    const float* W1  = (const float*)d_in[3];
    const float* aS1 = (const float*)d_in[4];
    const float* aD1 = (const float*)d_in[5];
    const float* We1 = (const float*)d_in[6];
    const float* aE1 = (const float*)d_in[7];
    const float* b1  = (const float*)d_in[8];
    const float* W2  = (const float*)d_in[9];
    const float* aS2 = (const float*)d_in[10];
    const float* aD2 = (const float*)d_in[11];
    const float* We2 = (const float*)d_in[12];
    const float* aE2 = (const float*)d_in[13];
    const float* b2  = (const float*)d_in[14];
    const float* W3  = (const float*)d_in[15];
    const float* aS3 = (const float*)d_in[16];
    const float* aD3 = (const float*)d_in[17];
    const float* We3 = (const float*)d_in[18];
    const float* aE3 = (const float*)d_in[19];
    const float* b3  = (const float*)d_in[20];

    const int* srcv = ei;
    const int* dstv = ei + NE;

    char* basep = (char*)d_ws;
    size_t off = 0;
    auto alloc = [&](size_t nbytes) -> void* {
        void* p = basep + off;
        off += (nbytes + 255) & ~(size_t)255;
        return p;
    };
    int*    bucket_cnt  = (int*)alloc((size_t)(NB + 1) * 4);
    int*    bucket_base = (int*)alloc((size_t)(NB + 1) * 4);
    int*    chunk_hist  = (int*)alloc((size_t)NCHUNK * NB * 4);   // 800 KB
    int*    chunk_base  = (int*)alloc((size_t)NCHUNK * NB * 4);   // 800 KB
    int*    rowptr      = (int*)alloc((size_t)(NN + 1) * 4);
    uint2*  binned      = (uint2*)alloc((size_t)NE * 8);
    unsigned char* dstb = (unsigned char*)alloc((size_t)NE);
    uint2*  edges       = (uint2*)alloc((size_t)NE * 8);
    float*  la          = (float*)alloc((size_t)NN * 8);
    float*  cbuf        = (float*)alloc(256);   // me1[0..7], me2[8..11], me3[12..13], vsd[16..55]
    float4* xp          = (float4*)alloc((size_t)NN * 32);
    float4* als1        = (float4*)alloc((size_t)NN * 16);
    float4* ald1        = (float4*)alloc((size_t)NN * 16);
    float*  xw          = (float*)alloc((size_t)NN * 80);
    unsigned short* h2q = (unsigned short*)alloc((size_t)NN * 128);
    float*  als2        = (float*)alloc((size_t)NN * 8);
    float*  ald2        = (float*)alloc((size_t)NN * 8);
    float*  h3          = (float*)alloc((size_t)NN * 4);
    unsigned short* W2th = (unsigned short*)alloc(64 * 128 * 2);
    unsigned short* W2tl = (unsigned short*)alloc(64 * 128 * 2);
    (void)ws_size; (void)in_sizes; (void)n_in; (void)out_size;

    float* me1 = cbuf;
    float* me2 = cbuf + 8;
    float* me3 = cbuf + 12;
    float* vsd = cbuf + 16;

    auto cdiv = [](long long a, long long b) { return (int)((a + b - 1) / b); };
    const int BS = 256;

    // ---- binned CSR build (la fused into binB) ----
    hipMemsetAsync(bucket_cnt, 0, (size_t)(NB + 1) * 4, stream);
    k_binA0<<<NCHUNK, 256, 0, stream>>>(dstv, bucket_cnt, chunk_hist, chunk_base);
    k_bscan<<<1, 512, 0, stream>>>(bucket_cnt, bucket_base);
    k_binA2<<<NCHUNK, 256, 0, stream>>>(srcv, dstv, ea, bucket_base, chunk_hist,
                                        chunk_base, binned, dstb);
    k_binB<<<NB, 256, 0, stream>>>(bucket_base, binned, dstb, rowptr, edges, la);

    // ---- all tiny constants + W2 transpose/split (single launch) ----
    k_constw<<<33, 256, 0, stream>>>(We1, aE1, We2, aE2, We3, aE3, W1, aS1, aD1,
                                     cbuf, W2, W2th, W2tl);

    // ================= Layer 1: IN=5, H=4, C=32 (ELU) =================
    k_prep1<<<cdiv(NN, BS), BS, 0, stream>>>(x, vsd, xp, als1, ald1);
    k_agg1<<<cdiv((long long)NN * 4, BS), BS, 0, stream>>>(rowptr, edges, xp,
                                                           (const float*)als1,
                                                           (const float*)ald1, la, me1, xw);

    // ================= Layer 2: in-register A-frag MFMA + agg =================
    k_l2mfma<<<NG, 64, 0, stream>>>(xw, W1, b1, W2th, W2tl, aS2, aD2,
                                    h2q, als2, ald2);
    k_agg2<<<cdiv((long long)NN * 4, BS), BS, 0, stream>>>(rowptr, edges, h2q, als2, ald2,
                                                           la, me2, b2, W3, h3);

    // ================= Layer 3: IN=64, H=1, C=1 (sigmoid) =================
    k_agg3<<<cdiv((long long)NN * 16, BS), BS, 0, stream>>>(rowptr, edges, h3, aS3, aD3,
                                                            la, me3, b3, (float*)d_out);
}

// Round 15
// 304.926 us; speedup vs baseline: 1.0412x; 1.0029x over previous
//
#include <hip/hip_runtime.h>
#include <math.h>

#define NN 100000
#define NE 1600000
#define NPB 256                     // nodes per bucket (dst >> 8)
#define NPB_SHIFT 8
#define NB ((NN + NPB - 1) / NPB)   // 391
#define NCHUNK 512                  // binning chunks
#define CH ((NE + NCHUNK - 1) / NCHUNK)  // 3125 edges per chunk
#define NG (NN / 16)                // 6250 MFMA node-groups (exact)
#define LOG2E 1.44269504088896f

typedef __attribute__((ext_vector_type(8))) short short8v;
typedef __attribute__((ext_vector_type(4))) float f32x4;

__device__ __forceinline__ float lrelu(float x) { return fmaxf(x, 0.2f * x); }
__device__ __forceinline__ float elu1(float x) { return x > 0.f ? x : (__expf(x) - 1.f); }
__device__ __forceinline__ float fexp2(float x) {
#if __has_builtin(__builtin_amdgcn_exp2f)
    return __builtin_amdgcn_exp2f(x);
#else
    return exp2f(x);
#endif
}
__device__ __forceinline__ unsigned bf16rne(float f) {
    unsigned u = __float_as_uint(f);
    return (u + 0x7FFFu + ((u >> 16) & 1u)) >> 16;
}
__device__ __forceinline__ float bf16lo(unsigned u) { return __uint_as_float(u << 16); }
__device__ __forceinline__ float bf16hi(unsigned u) {
    return __uint_as_float(u & 0xFFFF0000u);
}
// split x into hi+lo bf16 pair; pack two channels into dwords
__device__ __forceinline__ void split2(float x0, float x1, unsigned& hp, unsigned& lp) {
    unsigned h0 = bf16rne(x0), h1 = bf16rne(x1);
    float r0 = x0 - __uint_as_float(h0 << 16);
    float r1 = x1 - __uint_as_float(h1 << 16);
    hp = h0 | (h1 << 16);
    lp = bf16rne(r0) | (bf16rne(r1) << 16);
}
__device__ __forceinline__ float sel4(float4 v, int i) {
    return (i == 0) ? v.x : (i == 1) ? v.y : (i == 2) ? v.z : v.w;
}

// ================= binned CSR build =================
// A0: per-chunk histogram -> global (chunk_hist) + arrival-order base within each
// bucket (chunk_base, from the atomicAdd return). binA2 no longer re-histograms.
__global__ void __launch_bounds__(256) k_binA0(const int* __restrict__ dst,
                                               int* __restrict__ bucket_cnt,
                                               int* __restrict__ chunk_hist,
                                               int* __restrict__ chunk_base) {
    __shared__ int hist[NB];
    int t = threadIdx.x;
    for (int b = t; b < NB; b += 256) hist[b] = 0;
    __syncthreads();
    int c0 = blockIdx.x * CH, c1 = min(NE, c0 + CH);
    for (int e = c0 + t; e < c1; e += 256) atomicAdd(&hist[dst[e] >> NPB_SHIFT], 1);
    __syncthreads();
    int gb = blockIdx.x * NB;
    for (int b = t; b < NB; b += 256) {
        int h = hist[b];
        chunk_hist[gb + b] = h;
        chunk_base[gb + b] = h ? atomicAdd(&bucket_cnt[b], h) : 0;
    }
}

__global__ void __launch_bounds__(512) k_bscan(const int* __restrict__ bucket_cnt,
                                               int* __restrict__ bucket_base) {
    __shared__ int s[512];
    int t = threadIdx.x;
    int v = (t < NB) ? bucket_cnt[t] : 0;
    s[t] = v;
    __syncthreads();
    for (int off = 1; off < 512; off <<= 1) {
        int x = (t >= off) ? s[t - off] : 0;
        __syncthreads();
        if (t >= off) s[t] += x;
        __syncthreads();
    }
    if (t < NB) {
        int ex = s[t] - v;
        bucket_base[t] = ex;
        if (t == NB - 1) bucket_base[NB] = s[t];
    }
}

// A2: LDS counting sort of the chunk using the PRECOMPUTED per-chunk histogram
// (no dst re-read, no reservation atomics), then ordered coalesced write-out.
__global__ void __launch_bounds__(256) k_binA2(const int* __restrict__ src,
                                               const int* __restrict__ dst,
                                               const float* __restrict__ ea,
                                               const int* __restrict__ bucket_base,
                                               const int* __restrict__ chunk_hist,
                                               const int* __restrict__ chunk_base,
                                               uint2* __restrict__ binned,
                                               unsigned char* __restrict__ dstb) {
    __shared__ int pre[NB], cursor[NB], base_l[NB];
    __shared__ int psum[256];
    __shared__ uint2 lrec[CH];
    __shared__ int lds_d[CH];
    int t = threadIdx.x;
    int gb = blockIdx.x * NB;
    int c0 = blockIdx.x * CH, c1 = min(NE, c0 + CH);
    int cnt = c1 - c0;
    // local exclusive scan of the precomputed chunk histogram (2 buckets/thread)
    int b0 = t << 1, b1 = b0 + 1;
    int h0 = (b0 < NB) ? chunk_hist[gb + b0] : 0;
    int h1 = (b1 < NB) ? chunk_hist[gb + b1] : 0;
    psum[t] = h0 + h1;
    __syncthreads();
    for (int off = 1; off < 256; off <<= 1) {
        int x = (t >= off) ? psum[t - off] : 0;
        __syncthreads();
        if (t >= off) psum[t] += x;
        __syncthreads();
    }
    int ex = psum[t] - (h0 + h1);
    if (b0 < NB) {
        pre[b0] = ex;
        cursor[b0] = ex;
        base_l[b0] = bucket_base[b0] + chunk_base[gb + b0];
    }
    if (b1 < NB) {
        pre[b1] = ex + h0;
        cursor[b1] = ex + h0;
        base_l[b1] = bucket_base[b1] + chunk_base[gb + b1];
    }
    __syncthreads();
    // pass 2: scatter into LDS at sorted local positions
    for (int i = t; i < cnt; i += 256) {
        int e = c0 + i;
        int d = dst[e];
        int bkt = d >> NPB_SHIFT;
        int lpos = atomicAdd(&cursor[bkt], 1);
        unsigned pk = bf16rne(ea[2 * e]) | (bf16rne(ea[2 * e + 1]) << 16);
        lrec[lpos] = make_uint2((unsigned)src[e], pk);
        lds_d[lpos] = d;
    }
    __syncthreads();
    // pass 3: ordered write-out -> coalesced within bucket segments
    for (int i = t; i < cnt; i += 256) {
        int d = lds_d[i];
        int bkt = d >> NPB_SHIFT;
        int gpos = base_l[bkt] + (i - pre[bkt]);
        binned[gpos] = lrec[i];
        dstb[gpos] = (unsigned char)(d & (NPB - 1));
    }
}

// B: workgroup per bucket -> rowptr + final dst-sorted CSR + fused self-loop la
__global__ void __launch_bounds__(256) k_binB(const int* __restrict__ bucket_base,
                                              const uint2* __restrict__ binned,
                                              const unsigned char* __restrict__ dstb,
                                              int* __restrict__ rowptr,
                                              uint2* __restrict__ edges,
                                              float* __restrict__ la) {
    __shared__ int hist[NPB], pre[NPB], cursor[NPB];
    __shared__ float ea0s[NPB], ea1s[NPB];
    int b = blockIdx.x, t = threadIdx.x;
    int bb = bucket_base[b], be = bucket_base[b + 1];
    int nb0 = b << NPB_SHIFT;
    hist[t] = 0;
    ea0s[t] = 0.f;
    ea1s[t] = 0.f;
    __syncthreads();
    for (int e = bb + t; e < be; e += 256) atomicAdd(&hist[dstb[e]], 1);
    __syncthreads();
    int v = hist[t];
    pre[t] = v;
    __syncthreads();
    for (int off = 1; off < 256; off <<= 1) {
        int x = (t >= off) ? pre[t - off] : 0;
        __syncthreads();
        if (t >= off) pre[t] += x;
        __syncthreads();
    }
    int ex = pre[t] - v;
    if (nb0 + t <= NN) rowptr[nb0 + t] = bb + ex;
    cursor[t] = bb + ex;
    __syncthreads();
    for (int e = bb + t; e < be; e += 256) {
        uint2 rec = binned[e];
        unsigned char d = dstb[e];
        int pos = atomicAdd(&cursor[d], 1);
        edges[pos] = rec;
        atomicAdd(&ea0s[d], bf16lo(rec.y));
        atomicAdd(&ea1s[d], bf16hi(rec.y));
    }
    __syncthreads();
    int n = nb0 + t;
    if (n < NN) {
        float dg = fmaxf((float)v, 1.0f);
        la[2 * n] = ea0s[t] / dg;
        la[2 * n + 1] = ea1s[t] / dg;
    }
}

// ---------- fused constants + W2 transpose/split (one launch, 33 blocks) ----------
__global__ void __launch_bounds__(256) k_constw(
        const float* __restrict__ We1, const float* __restrict__ aE1,
        const float* __restrict__ We2, const float* __restrict__ aE2,
        const float* __restrict__ We3, const float* __restrict__ aE3,
        const float* __restrict__ W1, const float* __restrict__ aS1,
        const float* __restrict__ aD1, float* __restrict__ cbuf,
        const float* __restrict__ W2, unsigned short* __restrict__ W2th,
        unsigned short* __restrict__ W2tl) {
    if (blockIdx.x == 0) {
        int t = threadIdx.x;
        if (t < 8) {
            int d = t >> 2, hd = t & 3;
            float s = 0.f;
            for (int c = 0; c < 32; c++) s += We1[d * 128 + hd * 32 + c] * aE1[hd * 32 + c];
            cbuf[t] = s * LOG2E;
        } else if (t < 12) {
            int idx = t - 8, d = idx >> 1, hd = idx & 1;
            float s = 0.f;
            for (int c = 0; c < 32; c++) s += We2[d * 64 + hd * 32 + c] * aE2[hd * 32 + c];
            cbuf[t] = s * LOG2E;
        } else if (t < 14) {
            cbuf[t] = We3[t - 12] * aE3[0] * LOG2E;
        } else if (t >= 16 && t < 56) {
            int r = (t - 16) % 20, hd = r / 5, i = r % 5;
            const float* a = (t - 16 < 20) ? aS1 : aD1;
            float s = 0.f;
            for (int c = 0; c < 32; c++) s += W1[i * 128 + hd * 32 + c] * a[hd * 32 + c];
            cbuf[t] = s * LOG2E;
        }
    } else {
        int i = (blockIdx.x - 1) * 256 + threadIdx.x;
        if (i >= 64 * 128) return;
        int c = i >> 7, k = i & 127;
        float v = W2[k * 64 + c];
        unsigned h = bf16rne(v);
        float hf = __uint_as_float(h << 16);
        unsigned lo = bf16rne(v - hf);
        W2th[c * 128 + k] = (unsigned short)h;
        W2tl[c * 128 + k] = (unsigned short)lo;
    }
}

// layer-1 per-node: ONE 64B record per node = {x0..x3 | als1[0..3] | x4 | pad}.
// agg1's entire per-neighbor payload lives in a single aligned cache line.
__global__ void k_prep1(const float* __restrict__ x, const float* __restrict__ vsd,
                        float4* __restrict__ xpn, float4* __restrict__ ald1) {
    int n = blockIdx.x * blockDim.x + threadIdx.x;
    if (n >= NN) return;
    float x0 = x[5 * n], x1 = x[5 * n + 1], x2 = x[5 * n + 2], x3 = x[5 * n + 3],
          x4 = x[5 * n + 4];
    float sv[4], dv[4];
#pragma unroll
    for (int hd = 0; hd < 4; hd++) {
        const float* vS = vsd + hd * 5;
        const float* vD = vsd + 20 + hd * 5;
        sv[hd] = x0 * vS[0] + x1 * vS[1] + x2 * vS[2] + x3 * vS[3] + x4 * vS[4];
        dv[hd] = x0 * vD[0] + x1 * vD[1] + x2 * vD[2] + x3 * vD[3] + x4 * vD[4];
    }
    xpn[4 * n + 0] = make_float4(x0, x1, x2, x3);
    xpn[4 * n + 1] = make_float4(sv[0], sv[1], sv[2], sv[3]);
    xpn[4 * n + 2] = make_float4(x4, 0.f, 0.f, 0.f);
    ald1[n] = make_float4(dv[0], dv[1], dv[2], dv[3]);
}

// ---------- layer 1 agg: thread per (node, head); 4-edge batched, 1-line records ----
#define AGG1_EDGE(sa, sb, p)                                            \
    a0 += (p) * sa.x; a1 += (p) * sa.y; a2 += (p) * sa.z;               \
    a3 += (p) * sa.w; a4 += (p) * sb;

__global__ void k_agg1(const int* __restrict__ rowptr, const uint2* __restrict__ edges,
                       const float4* __restrict__ xpn, const float* __restrict__ ald1,
                       const float* __restrict__ la, const float* __restrict__ me,
                       float* __restrict__ xw) {
    int t = blockIdx.x * blockDim.x + threadIdx.x;
    if (t >= NN * 4) return;
    int n = t >> 2, hd = t & 3;
    float me0 = me[hd], me1 = me[4 + hd];
    float aldn = ald1[n * 4 + hd];
    float4 xa = xpn[4 * n];
    float4 lq = xpn[4 * n + 1];
    float xb = xpn[4 * n + 2].x;
    float aself = lrelu(sel4(lq, hd) + aldn + la[2 * n] * me0 + la[2 * n + 1] * me1);
    int start = rowptr[n], end = rowptr[n + 1];
    float den = 1.f;
    float a0 = xa.x, a1 = xa.y, a2 = xa.z, a3 = xa.w, a4 = xb;
    int e = start;
    if ((e & 1) && e < end) {
        uint2 ep = edges[e];
        int s = (int)ep.x;
        float4 sa = xpn[4 * s];
        float4 sl = xpn[4 * s + 1];
        float sb = xpn[4 * s + 2].x;
        float a = lrelu(sel4(sl, hd) + aldn + bf16lo(ep.y) * me0 + bf16hi(ep.y) * me1);
        float p = fexp2(a - aself);
        den += p;
        AGG1_EDGE(sa, sb, p)
        e++;
    }
    // 4-edge main loop: all loads issued before dependent compute (1 line per src)
    for (; e + 3 < end; e += 4) {
        uint4 twoA = *(const uint4*)(edges + e);
        uint4 twoB = *(const uint4*)(edges + e + 2);
        int s0 = (int)twoA.x, s1 = (int)twoA.z;
        int s2 = (int)twoB.x, s3 = (int)twoB.z;
        float4 sa0 = xpn[4 * s0]; float4 sl0 = xpn[4 * s0 + 1]; float sb0 = xpn[4 * s0 + 2].x;
        float4 sa1 = xpn[4 * s1]; float4 sl1 = xpn[4 * s1 + 1]; float sb1 = xpn[4 * s1 + 2].x;
        float4 sa2 = xpn[4 * s2]; float4 sl2 = xpn[4 * s2 + 1]; float sb2 = xpn[4 * s2 + 2].x;
        float4 sa3 = xpn[4 * s3]; float4 sl3 = xpn[4 * s3 + 1]; float sb3 = xpn[4 * s3 + 2].x;
        float av0 = lrelu(sel4(sl0, hd) + aldn + bf16lo(twoA.y) * me0 + bf16hi(twoA.y) * me1);
        float av1 = lrelu(sel4(sl1, hd) + aldn + bf16lo(twoA.w) * me0 + bf16hi(twoA.w) * me1);
        float av2 = lrelu(sel4(sl2, hd) + aldn + bf16lo(twoB.y) * me0 + bf16hi(twoB.y) * me1);
        float av3 = lrelu(sel4(sl3, hd) + aldn + bf16lo(twoB.w) * me0 + bf16hi(twoB.w) * me1);
        float p0 = fexp2(av0 - aself);
        float p1 = fexp2(av1 - aself);
        float p2 = fexp2(av2 - aself);
        float p3 = fexp2(av3 - aself);
        den += (p0 + p1) + (p2 + p3);
        a0 += p0 * sa0.x + p1 * sa1.x + p2 * sa2.x + p3 * sa3.x;
        a1 += p0 * sa0.y + p1 * sa1.y + p2 * sa2.y + p3 * sa3.y;
        a2 += p0 * sa0.z + p1 * sa1.z + p2 * sa2.z + p3 * sa3.z;
        a3 += p0 * sa0.w + p1 * sa1.w + p2 * sa2.w + p3 * sa3.w;
        a4 += p0 * sb0 + p1 * sb1 + p2 * sb2 + p3 * sb3;
    }
    if (e + 1 < end) {
        uint4 two = *(const uint4*)(edges + e);
        int s0 = (int)two.x, s1 = (int)two.z;
        float4 sa0 = xpn[4 * s0]; float4 sl0 = xpn[4 * s0 + 1]; float sb0 = xpn[4 * s0 + 2].x;
        float4 sa1 = xpn[4 * s1]; float4 sl1 = xpn[4 * s1 + 1]; float sb1 = xpn[4 * s1 + 2].x;
        float av0 = lrelu(sel4(sl0, hd) + aldn + bf16lo(two.y) * me0 + bf16hi(two.y) * me1);
        float av1 = lrelu(sel4(sl1, hd) + aldn + bf16lo(two.w) * me0 + bf16hi(two.w) * me1);
        float p0 = fexp2(av0 - aself);
        float p1 = fexp2(av1 - aself);
        den += p0 + p1;
        AGG1_EDGE(sa0, sb0, p0)
        AGG1_EDGE(sa1, sb1, p1)
        e += 2;
    }
    if (e < end) {
        uint2 ep = edges[e];
        int s = (int)ep.x;
        float4 sa = xpn[4 * s];
        float4 sl = xpn[4 * s + 1];
        float sb = xpn[4 * s + 2].x;
        float a = lrelu(sel4(sl, hd) + aldn + bf16lo(ep.y) * me0 + bf16hi(ep.y) * me1);
        float p = fexp2(a - aself);
        den += p;
        AGG1_EDGE(sa, sb, p)
    }
    float r = 1.f / den;
    float* w = xw + (size_t)n * 20 + hd * 5;
    w[0] = a0 * r;
    w[1] = a1 * r;
    w[2] = a2 * r;
    w[3] = a3 * r;
    w[4] = a4 * r;
}

// ---------- layer 2 transform: PURE MFMA, A-fragments IN-REGISTER ----------
// 1 wave per block (grid = NG): free wave placement across SIMDs, zero LDS.
__global__ void __launch_bounds__(64) k_l2mfma(
        const float* __restrict__ xw, const float* __restrict__ W1,
        const float* __restrict__ b1,
        const unsigned short* __restrict__ W2th, const unsigned short* __restrict__ W2tl,
        const float* __restrict__ aS2, const float* __restrict__ aD2,
        unsigned short* __restrict__ h2q, float* __restrict__ als2,
        float* __restrict__ ald2) {
    int l = threadIdx.x;
    int m = blockIdx.x;
    if (m >= NG) return;
    int g = l >> 4, row16 = l & 15;
    int anode = m * 16 + row16;
    // 20 xw values of this lane's A-node (5x float4, 80B)
    float w[20];
    {
        const float* wp = xw + (size_t)anode * 20;
#pragma unroll
        for (int i = 0; i < 5; ++i) {
            float4 v = *(const float4*)(wp + i * 4);
            w[i * 4 + 0] = v.x; w[i * 4 + 1] = v.y;
            w[i * 4 + 2] = v.z; w[i * 4 + 3] = v.w;
        }
    }
    f32x4 acc0 = {0.f, 0.f, 0.f, 0.f}, acc1 = acc0, acc2 = acc0, acc3 = acc0;
#pragma unroll
    for (int kt = 0; kt < 4; ++kt) {
        // ---- build A-fragment: act1 channels ch0..ch0+8 of anode ----
        int ch0 = kt * 32 + g * 8;
        float4 va = *(const float4*)(b1 + ch0);
        float4 vb = *(const float4*)(b1 + ch0 + 4);
#pragma unroll
        for (int i = 0; i < 5; ++i) {
            float wi = w[kt * 5 + i];
            float4 A = *(const float4*)(W1 + i * 128 + ch0);
            float4 B = *(const float4*)(W1 + i * 128 + ch0 + 4);
            va.x += wi * A.x; va.y += wi * A.y; va.z += wi * A.z; va.w += wi * A.w;
            vb.x += wi * B.x; vb.y += wi * B.y; vb.z += wi * B.z; vb.w += wi * B.w;
        }
        unsigned hp0, hp1, hp2, hp3, lp0, lp1, lp2, lp3;
        split2(elu1(va.x), elu1(va.y), hp0, lp0);
        split2(elu1(va.z), elu1(va.w), hp1, lp1);
        split2(elu1(vb.x), elu1(vb.y), hp2, lp2);
        split2(elu1(vb.z), elu1(vb.w), hp3, lp3);
        uint4 uh = make_uint4(hp0, hp1, hp2, hp3);
        uint4 ul = make_uint4(lp0, lp1, lp2, lp3);
        short8v ah = *(short8v*)&uh;
        short8v al = *(short8v*)&ul;
        int kb = kt * 32 + g * 8;
        {
            short8v bh = *(const short8v*)(W2th + row16 * 128 + kb);
            short8v bl = *(const short8v*)(W2tl + row16 * 128 + kb);
            acc0 = __builtin_amdgcn_mfma_f32_16x16x32_bf16(ah, bh, acc0, 0, 0, 0);
            acc0 = __builtin_amdgcn_mfma_f32_16x16x32_bf16(al, bh, acc0, 0, 0, 0);
            acc0 = __builtin_amdgcn_mfma_f32_16x16x32_bf16(ah, bl, acc0, 0, 0, 0);
        }
        {
            short8v bh = *(const short8v*)(W2th + (16 + row16) * 128 + kb);
            short8v bl = *(const short8v*)(W2tl + (16 + row16) * 128 + kb);
            acc1 = __builtin_amdgcn_mfma_f32_16x16x32_bf16(ah, bh, acc1, 0, 0, 0);
            acc1 = __builtin_amdgcn_mfma_f32_16x16x32_bf16(al, bh, acc1, 0, 0, 0);
            acc1 = __builtin_amdgcn_mfma_f32_16x16x32_bf16(ah, bl, acc1, 0, 0, 0);
        }
        {
            short8v bh = *(const short8v*)(W2th + (32 + row16) * 128 + kb);
            short8v bl = *(const short8v*)(W2tl + (32 + row16) * 128 + kb);
            acc2 = __builtin_amdgcn_mfma_f32_16x16x32_bf16(ah, bh, acc2, 0, 0, 0);
            acc2 = __builtin_amdgcn_mfma_f32_16x16x32_bf16(al, bh, acc2, 0, 0, 0);
            acc2 = __builtin_amdgcn_mfma_f32_16x16x32_bf16(ah, bl, acc2, 0, 0, 0);
        }
        {
            short8v bh = *(const short8v*)(W2th + (48 + row16) * 128 + kb);
            short8v bl = *(const short8v*)(W2tl + (48 + row16) * 128 + kb);
            acc3 = __builtin_amdgcn_mfma_f32_16x16x32_bf16(ah, bh, acc3, 0, 0, 0);
            acc3 = __builtin_amdgcn_mfma_f32_16x16x32_bf16(al, bh, acc3, 0, 0, 0);
            acc3 = __builtin_amdgcn_mfma_f32_16x16x32_bf16(ah, bl, acc3, 0, 0, 0);
        }
    }
    // epilogue (R6-verified). D layout: col = l&15 (=ch), row = g*4 + r (=node).
    {
        int nodeb = m * 16 + g * 4;
#pragma unroll
        for (int nt = 0; nt < 4; ++nt) {
            f32x4 A = (nt == 0) ? acc0 : (nt == 1) ? acc1 : (nt == 2) ? acc2 : acc3;
#pragma unroll
            for (int r = 0; r < 4; ++r) {
                float v = A[r];
                float u = __shfl_xor(v, 1);
                if (!(l & 1)) {
                    unsigned pk = bf16rne(v) | (bf16rne(u) << 16);
                    int node = nodeb + r;
                    int ch = nt * 16 + row16;   // even
                    *(unsigned*)(h2q + (size_t)node * 64 + ch) = pk;
                }
            }
        }
        float aSv0 = aS2[row16], aSv1 = aS2[16 + row16];
        float aSv2 = aS2[32 + row16], aSv3 = aS2[48 + row16];
        float aDv0 = aD2[row16], aDv1 = aD2[16 + row16];
        float aDv2 = aD2[32 + row16], aDv3 = aD2[48 + row16];
#pragma unroll
        for (int r = 0; r < 4; ++r) {
            float pS0 = acc0[r] * aSv0 + acc1[r] * aSv1;
            float pS1 = acc2[r] * aSv2 + acc3[r] * aSv3;
            float pD0 = acc0[r] * aDv0 + acc1[r] * aDv1;
            float pD1 = acc2[r] * aDv2 + acc3[r] * aDv3;
#pragma unroll
            for (int off = 1; off < 16; off <<= 1) {
                pS0 += __shfl_xor(pS0, off);
                pS1 += __shfl_xor(pS1, off);
                pD0 += __shfl_xor(pD0, off);
                pD1 += __shfl_xor(pD1, off);
            }
            if (row16 == 0) {
                int node = nodeb + r;
                als2[node * 2 + 0] = pS0 * LOG2E;
                als2[node * 2 + 1] = pS1 * LOG2E;
                ald2[node * 2 + 0] = pD0 * LOG2E;
                ald2[node * 2 + 1] = pD1 * LOG2E;
            }
        }
    }
}

// ---------- layer 2 agg: thread per (node, head-half); 4-edge batched for MLP ----------
#define AGG2_EDGE(u0, u1, p)                                            \
    acc[0] += (p) * bf16lo(u0.x); acc[1] += (p) * bf16hi(u0.x);         \
    acc[2] += (p) * bf16lo(u0.y); acc[3] += (p) * bf16hi(u0.y);         \
    acc[4] += (p) * bf16lo(u0.z); acc[5] += (p) * bf16hi(u0.z);         \
    acc[6] += (p) * bf16lo(u0.w); acc[7] += (p) * bf16hi(u0.w);         \
    acc[8] += (p) * bf16lo(u1.x); acc[9] += (p) * bf16hi(u1.x);         \
    acc[10] += (p) * bf16lo(u1.y); acc[11] += (p) * bf16hi(u1.y);       \
    acc[12] += (p) * bf16lo(u1.z); acc[13] += (p) * bf16hi(u1.z);       \
    acc[14] += (p) * bf16lo(u1.w); acc[15] += (p) * bf16hi(u1.w);

__global__ void k_agg2(const int* __restrict__ rowptr, const uint2* __restrict__ edges,
                       const unsigned short* __restrict__ h2q,
                       const float* __restrict__ als2, const float* __restrict__ ald2,
                       const float* __restrict__ la, const float* __restrict__ me,
                       const float* __restrict__ b2, const float* __restrict__ W3,
                       float* __restrict__ h3) {
    int t = blockIdx.x * blockDim.x + threadIdx.x;
    if (t >= NN * 4) return;
    int n = t >> 2, sub = t & 3, hd = sub >> 1, qh = sub & 1;
    int cbase = hd * 32 + qh * 16;
    float me0 = me[hd], me1 = me[2 + hd];
    float aldn = ald2[n * 2 + hd];
    float aself = lrelu(als2[n * 2 + hd] + aldn + la[2 * n] * me0 + la[2 * n + 1] * me1);
    int start = rowptr[n], end = rowptr[n + 1];
    float den = 1.f;
    float acc[16];
    {
        const uint4* hp = (const uint4*)(h2q + (size_t)n * 64 + cbase);
        uint4 u0 = hp[0], u1 = hp[1];
        acc[0] = bf16lo(u0.x); acc[1] = bf16hi(u0.x);
        acc[2] = bf16lo(u0.y); acc[3] = bf16hi(u0.y);
        acc[4] = bf16lo(u0.z); acc[5] = bf16hi(u0.z);
        acc[6] = bf16lo(u0.w); acc[7] = bf16hi(u0.w);
        acc[8] = bf16lo(u1.x); acc[9] = bf16hi(u1.x);
        acc[10] = bf16lo(u1.y); acc[11] = bf16hi(u1.y);
        acc[12] = bf16lo(u1.z); acc[13] = bf16hi(u1.z);
        acc[14] = bf16lo(u1.w); acc[15] = bf16hi(u1.w);
    }
    int e = start;
    if ((e & 1) && e < end) {
        uint2 ep = edges[e];
        int s = (int)ep.x;
        float a = lrelu(als2[s * 2 + hd] + aldn + bf16lo(ep.y) * me0 + bf16hi(ep.y) * me1);
        float p = fexp2(a - aself);
        den += p;
        const uint4* sp = (const uint4*)(h2q + (size_t)s * 64 + cbase);
        uint4 u0 = sp[0], u1 = sp[1];
        AGG2_EDGE(u0, u1, p)
        e++;
    }
    for (; e + 3 < end; e += 4) {
        uint4 twoA = *(const uint4*)(edges + e);
        uint4 twoB = *(const uint4*)(edges + e + 2);
        int s0 = (int)twoA.x, s1 = (int)twoA.z;
        int s2 = (int)twoB.x, s3 = (int)twoB.z;
        float l0 = als2[s0 * 2 + hd];
        float l1 = als2[s1 * 2 + hd];
        float l2 = als2[s2 * 2 + hd];
        float l3 = als2[s3 * 2 + hd];
        const uint4* sp0 = (const uint4*)(h2q + (size_t)s0 * 64 + cbase);
        const uint4* sp1 = (const uint4*)(h2q + (size_t)s1 * 64 + cbase);
        const uint4* sp2 = (const uint4*)(h2q + (size_t)s2 * 64 + cbase);
        const uint4* sp3 = (const uint4*)(h2q + (size_t)s3 * 64 + cbase);
        uint4 u00 = sp0[0], u01 = sp0[1];
        uint4 u10 = sp1[0], u11 = sp1[1];
        uint4 u20 = sp2[0], u21 = sp2[1];
        uint4 u30 = sp3[0], u31 = sp3[1];
        float av0 = lrelu(l0 + aldn + bf16lo(twoA.y) * me0 + bf16hi(twoA.y) * me1);
        float av1 = lrelu(l1 + aldn + bf16lo(twoA.w) * me0 + bf16hi(twoA.w) * me1);
        float av2 = lrelu(l2 + aldn + bf16lo(twoB.y) * me0 + bf16hi(twoB.y) * me1);
        float av3 = lrelu(l3 + aldn + bf16lo(twoB.w) * me0 + bf16hi(twoB.w) * me1);
        float p0 = fexp2(av0 - aself);
        float p1 = fexp2(av1 - aself);
        float p2 = fexp2(av2 - aself);
        float p3 = fexp2(av3 - aself);
        den += (p0 + p1) + (p2 + p3);
        acc[0] += p0 * bf16lo(u00.x) + p1 * bf16lo(u10.x) + p2 * bf16lo(u20.x) + p3 * bf16lo(u30.x);
        acc[1] += p0 * bf16hi(u00.x) + p1 * bf16hi(u10.x) + p2 * bf16hi(u20.x) + p3 * bf16hi(u30.x);
        acc[2] += p0 * bf16lo(u00.y) + p1 * bf16lo(u10.y) + p2 * bf16lo(u20.y) + p3 * bf16lo(u30.y);
        acc[3] += p0 * bf16hi(u00.y) + p1 * bf16hi(u10.y) + p2 * bf16hi(u20.y) + p3 * bf16hi(u30.y);
        acc[4] += p0 * bf16lo(u00.z) + p1 * bf16lo(u10.z) + p2 * bf16lo(u20.z) + p3 * bf16lo(u30.z);
        acc[5] += p0 * bf16hi(u00.z) + p1 * bf16hi(u10.z) + p2 * bf16hi(u20.z) + p3 * bf16hi(u30.z);
        acc[6] += p0 * bf16lo(u00.w) + p1 * bf16lo(u10.w) + p2 * bf16lo(u20.w) + p3 * bf16lo(u30.w);
        acc[7] += p0 * bf16hi(u00.w) + p1 * bf16hi(u10.w) + p2 * bf16hi(u20.w) + p3 * bf16hi(u30.w);
        acc[8] += p0 * bf16lo(u01.x) + p1 * bf16lo(u11.x) + p2 * bf16lo(u21.x) + p3 * bf16lo(u31.x);
        acc[9] += p0 * bf16hi(u01.x) + p1 * bf16hi(u11.x) + p2 * bf16hi(u21.x) + p3 * bf16hi(u31.x);
        acc[10] += p0 * bf16lo(u01.y) + p1 * bf16lo(u11.y) + p2 * bf16lo(u21.y) + p3 * bf16lo(u31.y);
        acc[11] += p0 * bf16hi(u01.y) + p1 * bf16hi(u11.y) + p2 * bf16hi(u21.y) + p3 * bf16hi(u31.y);
        acc[12] += p0 * bf16lo(u01.z) + p1 * bf16lo(u11.z) + p2 * bf16lo(u21.z) + p3 * bf16lo(u31.z);
        acc[13] += p0 * bf16hi(u01.z) + p1 * bf16hi(u11.z) + p2 * bf16hi(u21.z) + p3 * bf16hi(u31.z);
        acc[14] += p0 * bf16lo(u01.w) + p1 * bf16lo(u11.w) + p2 * bf16lo(u21.w) + p3 * bf16lo(u31.w);
        acc[15] += p0 * bf16hi(u01.w) + p1 * bf16hi(u11.w) + p2 * bf16hi(u21.w) + p3 * bf16hi(u31.w);
    }
    if (e + 1 < end) {
        uint4 two = *(const uint4*)(edges + e);
        int s0 = (int)two.x, s1 = (int)two.z;
        float l0 = als2[s0 * 2 + hd];
        float l1 = als2[s1 * 2 + hd];
        const uint4* sp0 = (const uint4*)(h2q + (size_t)s0 * 64 + cbase);
        const uint4* sp1 = (const uint4*)(h2q + (size_t)s1 * 64 + cbase);
        uint4 u00 = sp0[0], u01 = sp0[1];
        uint4 u10 = sp1[0], u11 = sp1[1];
        float av0 = lrelu(l0 + aldn + bf16lo(two.y) * me0 + bf16hi(two.y) * me1);
        float av1 = lrelu(l1 + aldn + bf16lo(two.w) * me0 + bf16hi(two.w) * me1);
        float p0 = fexp2(av0 - aself);
        float p1 = fexp2(av1 - aself);
        den += p0 + p1;
        AGG2_EDGE(u00, u01, p0)
        AGG2_EDGE(u10, u11, p1)
        e += 2;
    }
    if (e < end) {
        uint2 ep = edges[e];
        int s = (int)ep.x;
        float a = lrelu(als2[s * 2 + hd] + aldn + bf16lo(ep.y) * me0 + bf16hi(ep.y) * me1);
        float p = fexp2(a - aself);
        den += p;
        const uint4* sp = (const uint4*)(h2q + (size_t)s * 64 + cbase);
        uint4 u0 = sp[0], u1 = sp[1];
        AGG2_EDGE(u0, u1, p)
    }
    float r = 1.f / den;
    float part = 0.f;
#pragma unroll
    for (int c = 0; c < 16; c++) {
        float v = elu1(acc[c] * r + b2[cbase + c]);
        part += v * W3[cbase + c];
    }
    part += __shfl_xor(part, 1);
    part += __shfl_xor(part, 2);
    if (sub == 0) h3[n] = part;
}

// ---------- layer 3 agg: 16-lane group per node ----------
__global__ void k_agg3(const int* __restrict__ rowptr, const uint2* __restrict__ edges,
                       const float* __restrict__ h, const float* __restrict__ aS3,
                       const float* __restrict__ aD3, const float* __restrict__ la,
                       const float* __restrict__ me, const float* __restrict__ b,
                       float* __restrict__ out) {
    int tid = blockIdx.x * blockDim.x + threadIdx.x;
    int n = tid >> 4;
    if (n >= NN) return;
    int lane = tid & 15;
    float me0 = me[0], me1 = me[1];
    float aSs = aS3[0] * LOG2E, aDs = aD3[0] * LOG2E;
    float hn = h[n];
    float ald_n = hn * aDs;
    float aself = lrelu(hn * aSs + ald_n + la[2 * n] * me0 + la[2 * n + 1] * me1);
    int start = rowptr[n], end = rowptr[n + 1];
    float den = 0.f, num = 0.f;
    for (int e = start + lane; e < end; e += 16) {
        uint2 ep = edges[e];
        int s = (int)ep.x;
        float hv = h[s];
        float a = lrelu(hv * aSs + ald_n + bf16lo(ep.y) * me0 + bf16hi(ep.y) * me1);
        float p = fexp2(a - aself);
        den += p;
        num += p * hv;
    }
#pragma unroll
    for (int off = 8; off > 0; off >>= 1) {
        den += __shfl_xor(den, off);
        num += __shfl_xor(num, off);
    }
    if (lane == 0) {
        den += 1.f;
        num += hn;
        float v = num / den + b[0];
        out[n] = 1.f / (1.f + __expf(-v));
    }
}

extern "C" void kernel_launch(void* const* d_in, const int* in_sizes, int n_in,
                              void* d_out, int out_size, void* d_ws, size_t ws_size,
                              hipStream_t stream) {
    const float* x   = (const float*)d_in[0];
    const int*   ei  = (const int*)d_in[1];
    const float* ea  = (const float*)d_in[2];
    const float* W1  = (const float*)d_in[3];
    const float* aS1 = (const float*)d_in[4];
    const float* aD1 = (const float*)d_in[5];
    const float* We1 = (const float*)d_in[6];
    const float* aE1 = (const float*)d_in[7];
    const float* b1  = (const float*)d_in[8];
    const float* W2  = (const float*)d_in[9];
    const float* aS2 = (const float*)d_in[10];
    const float* aD2 = (const float*)d_in[11];
    const float* We2 = (const float*)d_in[12];
    const float* aE2 = (const float*)d_in[13];
    const float* b2  = (const float*)d_in[14];
    const float* W3  = (const float*)d_in[15];
    const float* aS3 = (const float*)d_in[16];
    const float* aD3 = (const float*)d_in[17];
    const float* We3 = (const float*)d_in[18];
    const float* aE3 = (const float*)d_in[19];
    const float* b3  = (const float*)d_in[20];

    const int* srcv = ei;
    const int* dstv = ei + NE;

    char* basep = (char*)d_ws;
    size_t off = 0;
    auto alloc = [&](size_t nbytes) -> void* {
        void* p = basep + off;
        off += (nbytes + 255) & ~(size_t)255;
        return p;
    };
    int*    bucket_cnt  = (int*)alloc((size_t)(NB + 1) * 4);
    int*    bucket_base = (int*)alloc((size_t)(NB + 1) * 4);
    int*    chunk_hist  = (int*)alloc((size_t)NCHUNK * NB * 4);   // 800 KB
    int*    chunk_base  = (int*)alloc((size_t)NCHUNK * NB * 4);   // 800 KB
    int*    rowptr      = (int*)alloc((size_t)(NN + 1) * 4);
    uint2*  binned      = (uint2*)alloc((size_t)NE * 8);
    unsigned char* dstb = (unsigned char*)alloc((size_t)NE);
    uint2*  edges       = (uint2*)alloc((size_t)NE * 8);
    float*  la          = (float*)alloc((size_t)NN * 8);
    float*  cbuf        = (float*)alloc(256);   // me1[0..7], me2[8..11], me3[12..13], vsd[16..55]
    float4* xpn         = (float4*)alloc((size_t)NN * 64);   // packed 64B node records
    float4* ald1        = (float4*)alloc((size_t)NN * 16);
    float*  xw          = (float*)alloc((size_t)NN * 80);
    unsigned short* h2q = (unsigned short*)alloc((size_t)NN * 128);
    float*  als2        = (float*)alloc((size_t)NN * 8);
    float*  ald2        = (float*)alloc((size_t)NN * 8);
    float*  h3          = (float*)alloc((size_t)NN * 4);
    unsigned short* W2th = (unsigned short*)alloc(64 * 128 * 2);
    unsigned short* W2tl = (unsigned short*)alloc(64 * 128 * 2);
    (void)ws_size; (void)in_sizes; (void)n_in; (void)out_size;

    float* me1 = cbuf;
    float* me2 = cbuf + 8;
    float* me3 = cbuf + 12;
    float* vsd = cbuf + 16;

    auto cdiv = [](long long a, long long b) { return (int)((a + b - 1) / b); };
    const int BS = 256;

    // ---- binned CSR build (la fused into binB) ----
    hipMemsetAsync(bucket_cnt, 0, (size_t)(NB + 1) * 4, stream);
    k_binA0<<<NCHUNK, 256, 0, stream>>>(dstv, bucket_cnt, chunk_hist, chunk_base);
    k_bscan<<<1, 512, 0, stream>>>(bucket_cnt, bucket_base);
    k_binA2<<<NCHUNK, 256, 0, stream>>>(srcv, dstv, ea, bucket_base, chunk_hist,
                                        chunk_base, binned, dstb);
    k_binB<<<NB, 256, 0, stream>>>(bucket_base, binned, dstb, rowptr, edges, la);

    // ---- all tiny constants + W2 transpose/split (single launch) ----
    k_constw<<<33, 256, 0, stream>>>(We1, aE1, We2, aE2, We3, aE3, W1, aS1, aD1,
                                     cbuf, W2, W2th, W2tl);

    // ================= Layer 1: IN=5, H=4, C=32 (ELU) =================
    k_prep1<<<cdiv(NN, BS), BS, 0, stream>>>(x, vsd, xpn, ald1);
    k_agg1<<<cdiv((long long)NN * 4, BS), BS, 0, stream>>>(rowptr, edges, xpn,
                                                           (const float*)ald1, la, me1, xw);

    // ================= Layer 2: in-register A-frag MFMA + agg =================
    k_l2mfma<<<NG, 64, 0, stream>>>(xw, W1, b1, W2th, W2tl, aS2, aD2,
                                    h2q, als2, ald2);
    k_agg2<<<cdiv((long long)NN * 4, BS), BS, 0, stream>>>(rowptr, edges, h2q, als2, ald2,
                                                           la, me2, b2, W3, h3);

    // ================= Layer 3: IN=64, H=1, C=1 (sigmoid) =================
    k_agg3<<<cdiv((long long)NN * 16, BS), BS, 0, stream>>>(rowptr, edges, h3, aS3, aD3,
                                                            la, me3, b3, (float*)d_out);
}